// Round 1
// baseline (3069.589 us; speedup 1.0000x reference)
//
#include <hip/hip_runtime.h>

#define H_ 4
#define O_ 32
#define HO 128
#define M_ 128
#define M2 256
#define D_ 16
#define B_ 1024
#define JIT 1e-4f

// ---------------------------------------------------------------------------
// prep: inverse lengthscales and sf2
__global__ void k_prep(const float* __restrict__ theta, float* __restrict__ LSI,
                       float* __restrict__ SF2) {
    int t = threadIdx.x;  // 64 threads
    if (t < H_ * D_) {
        int h = t / D_, d = t % D_;
        LSI[h * D_ + d] = __expf(-theta[h * (D_ + 1) + 1 + d]);
    }
    if (t < H_) SF2[t] = __expf(theta[t * (D_ + 1)]);
}

// scaled x rows + squared norms
__global__ void k_scale_x(const float* __restrict__ x, const float* __restrict__ LSI,
                          float* __restrict__ XS, float* __restrict__ XN) {
    int idx = blockIdx.x * 256 + threadIdx.x;  // h*B + b
    if (idx >= H_ * B_) return;
    int h = idx / B_, b = idx % B_;
    float s = 0.f;
#pragma unroll
    for (int d = 0; d < D_; d++) {
        float v = x[b * D_ + d] * LSI[h * D_ + d];
        XS[(long)idx * D_ + d] = v;
        s += v * v;
    }
    XN[idx] = s;
}

// scaled z_joint rows + squared norms ([z_old; z] per o, per h)
__global__ void k_scale_z(const float* __restrict__ z, const float* __restrict__ z_old,
                          const float* __restrict__ LSI, float* __restrict__ ZS,
                          float* __restrict__ ZN) {
    int idx = blockIdx.x * 256 + threadIdx.x;  // (h*O+o)*256 + i
    int i = idx & 255;
    int pair = idx >> 8;
    int h = pair >> 5, o = pair & 31;
    const float* src = (i < M_) ? (z_old + ((long)o * M_ + i) * D_)
                                : (z + ((long)o * M_ + (i - M_)) * D_);
    float s = 0.f;
#pragma unroll
    for (int d = 0; d < D_; d++) {
        float v = src[d] * LSI[h * D_ + d];
        ZS[(long)idx * D_ + d] = v;
        s += v * v;
    }
    ZN[idx] = s;
}

// unpack packed tril vec -> dense lower [O][128][128]
__global__ void k_unpack(const float* __restrict__ vec, float* __restrict__ UT) {
    long idx = (long)blockIdx.x * 256 + threadIdx.x;
    int o = (int)(idx >> 14);
    int e = (int)(idx & 16383);
    int i = e >> 7, j = e & 127;
    float v = (j <= i) ? vec[(long)o * (M_ * (M_ + 1) / 2) + i * (i + 1) / 2 + j] : 0.f;
    UT[idx] = v;
}

// kuu2 = k_rbf(z_joint, z_joint) + JIT*I   [HO][256][256]
__global__ __launch_bounds__(256) void k_kuu2(const float* __restrict__ ZS,
                                              const float* __restrict__ ZN,
                                              const float* __restrict__ SF2,
                                              float* __restrict__ K2) {
    int pair = blockIdx.x;
    int h = pair >> 5;
    int t = threadIdx.x;
    __shared__ float zs[M2][D_];
    __shared__ float zn[M2];
    for (int e = t; e < M2 * D_; e += 256) zs[e / D_][e % D_] = ZS[(long)pair * M2 * D_ + e];
    zn[t] = ZN[pair * M2 + t];
    __syncthreads();
    float sf2 = SF2[h];
    float my[D_];
#pragma unroll
    for (int d = 0; d < D_; d++) my[d] = zs[t][d];
    float myn = zn[t];
    for (int q = 0; q < M2; q++) {
        float dot = 0.f;
#pragma unroll
        for (int d = 0; d < D_; d++) dot += zs[q][d] * my[d];
        float d2 = fmaxf(zn[q] + myn - 2.f * dot, 0.f);
        float v = sf2 * __expf(-0.5f * d2);
        if (q == t) v += JIT;
        K2[(long)pair * M2 * M2 + (long)q * M2 + t] = v;
    }
}

// in-LDS packed Cholesky of the 128x128 TL block of K2 -> Lkuu (dense, zero upper)
__global__ __launch_bounds__(128) void k_chol128(const float* __restrict__ K2,
                                                 float* __restrict__ Lk) {
    int pair = blockIdx.x, t = threadIdx.x;
    __shared__ float Ap[M_ * (M_ + 1) / 2];
    const float* Asrc = K2 + (long)pair * M2 * M2;
    for (int e = t; e < M_ * (M_ + 1) / 2; e += 128) {
        int i = (int)((sqrtf(8.f * e + 1.f) - 1.f) * 0.5f);
        while ((i + 1) * (i + 2) / 2 <= e) i++;
        while (i * (i + 1) / 2 > e) i--;
        int j = e - i * (i + 1) / 2;
        Ap[e] = Asrc[(long)i * M2 + j];
    }
    __syncthreads();
    for (int k = 0; k < M_; k++) {
        float s = sqrtf(Ap[k * (k + 1) / 2 + k]);
        float rinv = 1.f / s;
        __syncthreads();
        int i = k + 1 + t;
        float aik = 0.f;
        if (i < M_) {
            aik = Ap[i * (i + 1) / 2 + k] * rinv;
            Ap[i * (i + 1) / 2 + k] = aik;
        }
        if (t == 0) Ap[k * (k + 1) / 2 + k] = s;
        __syncthreads();
        if (i < M_) {
            for (int j = k + 1; j <= i; j++) Ap[i * (i + 1) / 2 + j] -= aik * Ap[j * (j + 1) / 2 + k];
        }
        __syncthreads();
    }
    for (int e = t; e < M_ * M_; e += 128) {
        int i = e >> 7, j = e & 127;
        Lk[(long)pair * M_ * M_ + e] = (j <= i) ? Ap[i * (i + 1) / 2 + j] : 0.f;
    }
}

// blocked (64-panel) in-place Cholesky of a 256x256 matrix kept in global; zeros upper.
// grid 2*HO: first HO blocks -> M0 (cov_joint), next HO -> M1 (kuu2)
__global__ __launch_bounds__(256) void k_cholB(float* __restrict__ M0, float* __restrict__ M1) {
    int bid = blockIdx.x;
    float* A = (bid < HO) ? (M0 + (long)bid * M2 * M2) : (M1 + (long)(bid - HO) * M2 * M2);
    int t = threadIdx.x;
    __shared__ float Dp[64 * 65 / 2];
    __shared__ float Pp[192][66];
    for (int kb = 0; kb < 4; kb++) {
        int c0 = kb * 64;
        int S = 256 - c0 - 64;
        // load diag block (packed)
        for (int e = t; e < 2080; e += 256) {
            int i = (int)((sqrtf(8.f * e + 1.f) - 1.f) * 0.5f);
            while ((i + 1) * (i + 2) / 2 <= e) i++;
            while (i * (i + 1) / 2 > e) i--;
            int j = e - i * (i + 1) / 2;
            Dp[e] = A[(long)(c0 + i) * M2 + c0 + j];
        }
        __syncthreads();
        // chol of 64x64 D
        for (int k = 0; k < 64; k++) {
            float s = sqrtf(Dp[k * (k + 1) / 2 + k]);
            float rinv = 1.f / s;
            __syncthreads();
            int i = k + 1 + t;
            float aik = 0.f;
            if (i < 64) {
                aik = Dp[i * (i + 1) / 2 + k] * rinv;
                Dp[i * (i + 1) / 2 + k] = aik;
            }
            if (t == 0) Dp[k * (k + 1) / 2 + k] = s;
            __syncthreads();
            if (i < 64) {
                for (int j = k + 1; j <= i; j++) Dp[i * (i + 1) / 2 + j] -= aik * Dp[j * (j + 1) / 2 + k];
            }
            __syncthreads();
        }
        // write D back (zero its upper)
        for (int e = t; e < 4096; e += 256) {
            int i = e >> 6, j = e & 63;
            A[(long)(c0 + i) * M2 + c0 + j] = (j <= i) ? Dp[i * (i + 1) / 2 + j] : 0.f;
        }
        __syncthreads();
        if (S > 0) {
            // load panel
            for (int e = t; e < S * 64; e += 256) {
                int r = e >> 6, j = e & 63;
                Pp[r][j] = A[(long)(c0 + 64 + r) * M2 + c0 + j];
            }
            __syncthreads();
            // row-wise trsm: X = P * Ld^{-T}
            for (int r = t; r < S; r += 256) {
                for (int j = 0; j < 64; j++) {
                    float acc = Pp[r][j];
                    for (int q = 0; q < j; q++) acc -= Pp[r][q] * Dp[j * (j + 1) / 2 + q];
                    Pp[r][j] = acc / Dp[j * (j + 1) / 2 + j];
                }
            }
            __syncthreads();
            // write panel back
            for (int e = t; e < S * 64; e += 256) {
                int r = e >> 6, j = e & 63;
                A[(long)(c0 + 64 + r) * M2 + c0 + j] = Pp[r][j];
            }
            // trailing update C -= X X^T (full square of trailing region)
            int c1 = c0 + 64;
            for (int i = 0; i < S; i++) {
                for (int j = t; j < S; j += 256) {
                    float acc = 0.f;
#pragma unroll 16
                    for (int q = 0; q < 64; q++) acc += Pp[i][q] * Pp[j][q];
                    A[(long)(c1 + i) * M2 + c1 + j] -= acc;
                }
            }
            __syncthreads();
        }
    }
    // zero strict upper triangle
    for (int e = t; e < M2 * M2; e += 256) {
        int i = e >> 8, j = e & 255;
        if (j > i) A[e] = 0.f;
    }
}

// invert 64x64 lower-tri diagonal blocks: grid (nPair, NB), 64 threads
__global__ __launch_bounds__(64) void k_diaginv(const float* __restrict__ L, long sPair, int ld,
                                                float* __restrict__ Out, long sPairO, int ldo) {
    int pair = blockIdx.x, I0 = blockIdx.y * 64;
    int c = threadIdx.x;
    __shared__ float Ld[64][66];
    __shared__ float Wd[64][66];
    const float* Lp = L + (long)pair * sPair + (long)I0 * ld + I0;
    for (int e = c; e < 4096; e += 64) {
        int i = e >> 6, j = e & 63;
        Ld[i][j] = Lp[(long)i * ld + j];
    }
    __syncthreads();
    for (int i = 0; i < 64; i++) {
        float acc = (i == c) ? 1.f : 0.f;
        for (int j = 0; j < i; j++) acc -= Ld[i][j] * Wd[j][c];
        Wd[i][c] = acc / Ld[i][i];
    }
    float* Op = Out + (long)pair * sPairO + (long)I0 * ldo + I0;
    for (int i = 0; i < 64; i++) Op[(long)i * ldo + c] = Wd[i][c];
}

// off-diagonal blocks of triangular inverse: Linv_IJ = -Dinv_I * sum_{K=J..I-1} L_IK Linv_KJ
// grid (nPair, NB-d), 256 threads
__global__ __launch_bounds__(256) void k_linvoff(const float* __restrict__ L, long sPair, int ld,
                                                 float* __restrict__ Linv, long sPairO, int ldo,
                                                 int d) {
    int pair = blockIdx.x, J = blockIdx.y, I = J + d;
    int I0 = I * 64, J0 = J * 64;
    int t = threadIdx.x, tx = t & 15, ty = t >> 4;
    __shared__ float La[64][66], Lb[64][66], Ss[64][66];
    float acc[4][4] = {};
    for (int K = J; K < I; K++) {
        int K0 = K * 64;
        for (int e = t; e < 4096; e += 256) {
            int i = e >> 6, k = e & 63;
            La[i][k] = L[(long)pair * sPair + (long)(I0 + i) * ld + K0 + k];
            Lb[i][k] = Linv[(long)pair * sPairO + (long)(K0 + i) * ldo + J0 + k];
        }
        __syncthreads();
#pragma unroll 4
        for (int kk = 0; kk < 64; kk++) {
            float a[4], b[4];
#pragma unroll
            for (int q = 0; q < 4; q++) { a[q] = La[ty + 16 * q][kk]; b[q] = Lb[kk][tx + 16 * q]; }
#pragma unroll
            for (int q = 0; q < 4; q++)
#pragma unroll
                for (int r = 0; r < 4; r++) acc[q][r] += a[q] * b[r];
        }
        __syncthreads();
    }
#pragma unroll
    for (int q = 0; q < 4; q++)
#pragma unroll
        for (int r = 0; r < 4; r++) Ss[ty + 16 * q][tx + 16 * r] = acc[q][r];
    for (int e = t; e < 4096; e += 256) {
        int i = e >> 6, k = e & 63;
        La[i][k] = Linv[(long)pair * sPairO + (long)(I0 + i) * ldo + I0 + k];
    }
    __syncthreads();
    float out[4][4] = {};
#pragma unroll 4
    for (int kk = 0; kk < 64; kk++) {
        float a[4], b[4];
#pragma unroll
        for (int q = 0; q < 4; q++) { a[q] = La[ty + 16 * q][kk]; b[q] = Ss[kk][tx + 16 * q]; }
#pragma unroll
        for (int q = 0; q < 4; q++)
#pragma unroll
            for (int r = 0; r < 4; r++) out[q][r] += a[q] * b[r];
    }
#pragma unroll
    for (int q = 0; q < 4; q++)
#pragma unroll
        for (int r = 0; r < 4; r++)
            Linv[(long)pair * sPairO + (long)(I0 + ty + 16 * q) * ldo + J0 + tx + 16 * r] = -out[q][r];
}

// a2 = Linv128 * m_old ; m_new = A1^T a2 + u_mean ; write m_joint
__global__ __launch_bounds__(128) void k_stage1vec(const float* __restrict__ Linv128,
                                                   const float* __restrict__ A1,
                                                   const float* __restrict__ m_old,
                                                   const float* __restrict__ u_mean,
                                                   float* __restrict__ MJ) {
    int pair = blockIdx.x, o = pair & 31, t = threadIdx.x;
    __shared__ float mo[128], a2[128];
    mo[t] = m_old[o * 128 + t];
    __syncthreads();
    const float* Lr = Linv128 + (long)pair * 16384 + (long)t * 128;
    float acc = 0.f;
    for (int j = 0; j <= t; j++) acc += Lr[j] * mo[j];
    a2[t] = acc;
    __syncthreads();
    float m = 0.f;
    for (int i = 0; i < 128; i++) m += A1[(long)pair * 16384 + (long)i * 128 + t] * a2[i];
    MJ[pair * 256 + t] = mo[t];
    MJ[pair * 256 + 128 + t] = m + u_mean[o * 128 + t];
}

// assemble cov_joint quadrants
__global__ __launch_bounds__(256) void k_assemble(const float* __restrict__ SOLD,
                                                  const float* __restrict__ SCUR,
                                                  const float* __restrict__ TRb,
                                                  const float* __restrict__ BRb,
                                                  float* __restrict__ COV) {
    int pair = blockIdx.x, quad = blockIdx.y, o = pair & 31, t = threadIdx.x;
    long base = (long)pair * M2 * M2;
    for (int e = t; e < 16384; e += 256) {
        int i = e >> 7, j = e & 127;
        if (quad == 0) {
            COV[base + (long)i * 256 + j] = SOLD[(long)o * 16384 + e] + ((i == j) ? JIT : 0.f);
        } else if (quad == 1) {
            COV[base + (long)i * 256 + 128 + j] = TRb[(long)pair * 16384 + e];
        } else if (quad == 2) {
            COV[base + (long)(128 + i) * 256 + j] = TRb[(long)pair * 16384 + (long)j * 128 + i];
        } else {
            COV[base + (long)(128 + i) * 256 + 128 + j] =
                SCUR[(long)o * 16384 + e] + BRb[(long)pair * 16384 + e] + ((i == j) ? JIT : 0.f);
        }
    }
}

// c = Linv^T (Linv * m_joint)
__global__ __launch_bounds__(256) void k_cvec(const float* __restrict__ Linv,
                                              const float* __restrict__ MJ,
                                              float* __restrict__ CV) {
    int pair = blockIdx.x, t = threadIdx.x;
    __shared__ float mj[256], tmp[256];
    mj[t] = MJ[pair * 256 + t];
    __syncthreads();
    const float* Lp = Linv + (long)pair * 65536;
    float acc = 0.f;
    for (int j = 0; j <= t; j++) acc += Lp[(long)t * 256 + j] * mj[j];
    tmp[t] = acc;
    __syncthreads();
    float c = 0.f;
    for (int k = t; k < 256; k++) c += Lp[(long)k * 256 + t] * tmp[k];
    CV[pair * 256 + t] = c;
}

// generic batched SGEMM: C = alpha * opA(A) * opB(B) (+ C if accum)
// A' = TA ? A[k][m] : A[m][k];  B' = TB ? B[n][k] : B[k][n]
// tile 128x128, BK=16, 256 threads, 8x8 per thread; per-operand (h,o) strides.
template <int TA, int TB>
__global__ __launch_bounds__(256) void k_bmm(const float* __restrict__ A, long aSH, long aSO, int lda,
                                             const float* __restrict__ B, long bSH, long bSO, int ldb,
                                             float* __restrict__ C, long cSH, long cSO, int ldc,
                                             int Ksz, int kLoMode, int kHiMode, float alpha, int accum) {
    int pair = blockIdx.x;
    int h = pair >> 5, o = pair & 31;
    const float* Ap = A + (long)h * aSH + (long)o * aSO;
    const float* Bp = B + (long)h * bSH + (long)o * bSO;
    float* Cp = C + (long)h * cSH + (long)o * cSO;
    int I0 = blockIdx.y * 128, J0 = blockIdx.z * 128;
    int k0 = (kLoMode == 0) ? 0 : (kLoMode == 1) ? I0 : (kLoMode == 2) ? J0 : max(I0, J0);
    int k1 = (kHiMode == 0) ? Ksz : (kHiMode == 1) ? min(Ksz, I0 + 128) : min(Ksz, min(I0, J0) + 128);
    int t = threadIdx.x, tx = t & 15, ty = t >> 4;
    __shared__ float As[16][132], Bs[16][132];
    float acc[8][8] = {};
    for (int kt = k0; kt < k1; kt += 16) {
#pragma unroll
        for (int q = 0; q < 8; q++) {
            int e = q * 256 + t;
            if (TA) {
                int kk = e >> 7, m = e & 127;
                As[kk][m] = Ap[(long)(kt + kk) * lda + I0 + m];
            } else {
                int m = e >> 4, kk = e & 15;
                As[kk][m] = Ap[(long)(I0 + m) * lda + kt + kk];
            }
            if (TB) {
                int n = e >> 4, kk = e & 15;
                Bs[kk][n] = Bp[(long)(J0 + n) * ldb + kt + kk];
            } else {
                int kk = e >> 7, n = e & 127;
                Bs[kk][n] = Bp[(long)(kt + kk) * ldb + J0 + n];
            }
        }
        __syncthreads();
#pragma unroll
        for (int kk = 0; kk < 16; kk++) {
            float a[8], b[8];
#pragma unroll
            for (int q = 0; q < 8; q++) { a[q] = As[kk][ty + 16 * q]; b[q] = Bs[kk][tx + 16 * q]; }
#pragma unroll
            for (int q = 0; q < 8; q++)
#pragma unroll
                for (int r = 0; r < 8; r++) acc[q][r] += a[q] * b[r];
        }
        __syncthreads();
    }
#pragma unroll
    for (int q = 0; q < 8; q++)
#pragma unroll
        for (int r = 0; r < 8; r++) {
            long idx = (long)(I0 + ty + 16 * q) * ldc + J0 + tx + 16 * r;
            float v = alpha * acc[q][r];
            if (accum) v += Cp[idx];
            Cp[idx] = v;
        }
}

// fused final kernel: per (pair, 64-col b-tile): build K tile in LDS,
// q[b] = K^T G K (diag), mu[b] = K^T c, var = sf2 - q
__global__ __launch_bounds__(256) void k_kb2(const float* __restrict__ ZS, const float* __restrict__ ZN,
                                             const float* __restrict__ XS, const float* __restrict__ XN,
                                             const float* __restrict__ SF2, const float* __restrict__ G,
                                             const float* __restrict__ CV, float* __restrict__ out) {
    int btile = blockIdx.x;  // 16
    int pair = blockIdx.y;   // 128
    int h = pair >> 5;
    int t = threadIdx.x;
    int c = t & 63;
    int r = __builtin_amdgcn_readfirstlane(t >> 6);  // wave id, force SGPR
    int b = btile * 64 + c;
    __shared__ float Ks[256][64];  // exactly 64 KB
    float xs[16];
#pragma unroll
    for (int d = 0; d < 16; d++) xs[d] = XS[((long)h * B_ + b) * 16 + d];
    float xn = XN[h * B_ + b];
    float sf2 = SF2[h];
    const float* zsp = ZS + (long)pair * 256 * 16;
    const float* znp = ZN + pair * 256;
    for (int i = r * 64; i < r * 64 + 64; i++) {
        float dot = 0.f;
#pragma unroll
        for (int d = 0; d < 16; d++) dot += zsp[(long)i * 16 + d] * xs[d];
        float d2 = fmaxf(znp[i] + xn - 2.f * dot, 0.f);
        Ks[i][c] = sf2 * __expf(-0.5f * d2);
    }
    __syncthreads();
    const float* Gp = G + (long)pair * 65536;
    const float* cvp = CV + pair * 256;
    float qacc = 0.f, macc = 0.f;
    for (int i4 = 0; i4 < 16; i4++) {
        int i0 = r * 64 + i4 * 4;
        float y0 = 0.f, y1 = 0.f, y2 = 0.f, y3 = 0.f;
        const float* g0 = Gp + (long)i0 * 256;
        const float* g1 = g0 + 256;
        const float* g2 = g0 + 512;
        const float* g3 = g0 + 768;
#pragma unroll 4
        for (int j = 0; j < 256; j++) {
            float kv = Ks[j][c];
            y0 += g0[j] * kv;
            y1 += g1[j] * kv;
            y2 += g2[j] * kv;
            y3 += g3[j] * kv;
        }
        qacc += Ks[i0][c] * y0 + Ks[i0 + 1][c] * y1 + Ks[i0 + 2][c] * y2 + Ks[i0 + 3][c] * y3;
        macc += Ks[i0][c] * cvp[i0] + Ks[i0 + 1][c] * cvp[i0 + 1] + Ks[i0 + 2][c] * cvp[i0 + 2] +
                Ks[i0 + 3][c] * cvp[i0 + 3];
    }
    __syncthreads();  // done reading Ks; reuse as reduction buffer
    float* red = &Ks[0][0];
    red[r * 64 + c] = qacc;
    red[256 + r * 64 + c] = macc;
    __syncthreads();
    if (t < 64) {
        float q = red[t] + red[64 + t] + red[128 + t] + red[192 + t];
        float m = red[256 + t] + red[320 + t] + red[384 + t] + red[448 + t];
        long ob = (long)pair * 1024 + btile * 64 + t;
        out[ob] = m;
        out[(long)H_ * O_ * B_ + ob] = sf2 - q;
    }
}

// ---------------------------------------------------------------------------
extern "C" void kernel_launch(void* const* d_in, const int* in_sizes, int n_in,
                              void* d_out, int out_size, void* d_ws, size_t ws_size,
                              hipStream_t stream) {
    const float* x = (const float*)d_in[0];
    const float* z = (const float*)d_in[1];
    const float* u_mean = (const float*)d_in[2];
    const float* u_tril_vec = (const float*)d_in[3];
    const float* m_old = (const float*)d_in[4];
    const float* L_old = (const float*)d_in[5];
    const float* z_old = (const float*)d_in[6];
    const float* theta = (const float*)d_in[7];

    const long BIGSZ = (long)HO * M2 * M2;  // 8388608
    const long MSZ = (long)HO * M_ * M_;    // 2097152
    const long OSZ = (long)O_ * M_ * M_;    // 524288

    float* ws = (float*)d_ws;
    long off = 0;
    float* BIG0 = ws + off; off += BIGSZ;  // KUU2 -> Lk2 -> G
    float* BIG1 = ws + off; off += BIGSZ;  // UT -> COV/L_joint -> R
    float* BIG2 = ws + off; off += BIGSZ;  // A1|A3|ATX -> Linv
    float* BIG3 = ws + off; off += BIGSZ;  // Lkuu|Linv128|TRb|BRb -> T
    float* SOLD = ws + off; off += OSZ;
    float* SCUR = ws + off; off += OSZ;
    float* ZS = ws + off; off += (long)HO * M2 * D_;
    float* XS = ws + off; off += (long)H_ * B_ * D_;
    float* ZN = ws + off; off += (long)HO * M2;
    float* XN = ws + off; off += (long)H_ * B_;
    float* MJ = ws + off; off += (long)HO * M2;
    float* CV = ws + off; off += (long)HO * M2;
    float* LSI = ws + off; off += H_ * D_;
    float* SF2v = ws + off; off += H_;

    float* UT = BIG1;
    float* KUU2 = BIG0;
    float* COV = BIG1;
    float* A1 = BIG2;
    float* A3 = BIG2 + MSZ;
    float* ATX = BIG2 + 2 * MSZ;
    float* Lkuu = BIG3;
    float* Linv128 = BIG3 + MSZ;
    float* TRb = BIG3 + 2 * MSZ;
    float* BRb = BIG3 + 3 * MSZ;
    float* LINV = BIG2;
    float* Tb = BIG3;
    float* Rb = BIG1;
    float* Gb = BIG0;

    k_prep<<<1, 64, 0, stream>>>(theta, LSI, SF2v);
    k_scale_x<<<(H_ * B_ + 255) / 256, 256, 0, stream>>>(x, LSI, XS, XN);
    k_scale_z<<<HO * M2 / 256, 256, 0, stream>>>(z, z_old, LSI, ZS, ZN);
    k_unpack<<<(int)(OSZ / 256), 256, 0, stream>>>(u_tril_vec, UT);

    // S_old = L_old L_old^T ; S_cur = UT UT^T   (batched over o)
    k_bmm<0, 1><<<dim3(O_, 1, 1), 256, 0, stream>>>(L_old, 0, (long)M_ * M_, M_,
                                                    L_old, 0, (long)M_ * M_, M_,
                                                    SOLD, 0, (long)M_ * M_, M_, M_, 0, 0, 1.f, 0);
    k_bmm<0, 1><<<dim3(O_, 1, 1), 256, 0, stream>>>(UT, 0, (long)M_ * M_, M_,
                                                    UT, 0, (long)M_ * M_, M_,
                                                    SCUR, 0, (long)M_ * M_, M_, M_, 0, 0, 1.f, 0);

    k_kuu2<<<HO, 256, 0, stream>>>(ZS, ZN, SF2v, KUU2);
    k_chol128<<<HO, 128, 0, stream>>>(KUU2, Lkuu);

    hipMemsetAsync(Linv128, 0, MSZ * sizeof(float), stream);
    k_diaginv<<<dim3(HO, 2), 64, 0, stream>>>(Lkuu, (long)M_ * M_, M_, Linv128, (long)M_ * M_, M_);
    k_linvoff<<<dim3(HO, 1), 256, 0, stream>>>(Lkuu, (long)M_ * M_, M_, Linv128, (long)M_ * M_, M_, 1);

    // A1 = Linv128 @ kuf (kuf = KUU2 cols 128..255, rows 0..127)
    k_bmm<0, 0><<<dim3(HO, 1, 1), 256, 0, stream>>>(Linv128, (long)O_ * M_ * M_, (long)M_ * M_, M_,
                                                    KUU2 + 128, (long)O_ * M2 * M2, (long)M2 * M2, M2,
                                                    A1, (long)O_ * M_ * M_, (long)M_ * M_, M_, M_, 0, 0, 1.f, 0);
    // A3 = Linv128 @ L_old
    k_bmm<0, 0><<<dim3(HO, 1, 1), 256, 0, stream>>>(Linv128, (long)O_ * M_ * M_, (long)M_ * M_, M_,
                                                    L_old, 0, (long)M_ * M_, M_,
                                                    A3, (long)O_ * M_ * M_, (long)M_ * M_, M_, M_, 0, 0, 1.f, 0);
    k_stage1vec<<<HO, 128, 0, stream>>>(Linv128, A1, m_old, u_mean, MJ);

    // ATX = A3^T @ A1
    k_bmm<1, 0><<<dim3(HO, 1, 1), 256, 0, stream>>>(A3, (long)O_ * M_ * M_, (long)M_ * M_, M_,
                                                    A1, (long)O_ * M_ * M_, (long)M_ * M_, M_,
                                                    ATX, (long)O_ * M_ * M_, (long)M_ * M_, M_, M_, 0, 0, 1.f, 0);
    // TRb = L_old @ ATX
    k_bmm<0, 0><<<dim3(HO, 1, 1), 256, 0, stream>>>(L_old, 0, (long)M_ * M_, M_,
                                                    ATX, (long)O_ * M_ * M_, (long)M_ * M_, M_,
                                                    TRb, (long)O_ * M_ * M_, (long)M_ * M_, M_, M_, 0, 0, 1.f, 0);
    // BRb = ATX^T @ ATX
    k_bmm<1, 0><<<dim3(HO, 1, 1), 256, 0, stream>>>(ATX, (long)O_ * M_ * M_, (long)M_ * M_, M_,
                                                    ATX, (long)O_ * M_ * M_, (long)M_ * M_, M_,
                                                    BRb, (long)O_ * M_ * M_, (long)M_ * M_, M_, M_, 0, 0, 1.f, 0);

    k_assemble<<<dim3(HO, 4), 256, 0, stream>>>(SOLD, SCUR, TRb, BRb, COV);

    // chol of COV (-> L_joint) and KUU2 (-> Lk2), one launch
    k_cholB<<<2 * HO, 256, 0, stream>>>(COV, KUU2);

    hipMemsetAsync(LINV, 0, BIGSZ * sizeof(float), stream);
    k_diaginv<<<dim3(HO, 4), 64, 0, stream>>>(KUU2, (long)M2 * M2, M2, LINV, (long)M2 * M2, M2);
    k_linvoff<<<dim3(HO, 3), 256, 0, stream>>>(KUU2, (long)M2 * M2, M2, LINV, (long)M2 * M2, M2, 1);
    k_linvoff<<<dim3(HO, 2), 256, 0, stream>>>(KUU2, (long)M2 * M2, M2, LINV, (long)M2 * M2, M2, 2);
    k_linvoff<<<dim3(HO, 1), 256, 0, stream>>>(KUU2, (long)M2 * M2, M2, LINV, (long)M2 * M2, M2, 3);

    k_cvec<<<HO, 256, 0, stream>>>(LINV, MJ, CV);

    // T = Linv @ L_joint (lower):   k in [J0, I0+128)
    k_bmm<0, 0><<<dim3(HO, 2, 2), 256, 0, stream>>>(LINV, (long)O_ * M2 * M2, (long)M2 * M2, M2,
                                                    COV, (long)O_ * M2 * M2, (long)M2 * M2, M2,
                                                    Tb, (long)O_ * M2 * M2, (long)M2 * M2, M2, M2, 2, 1, 1.f, 0);
    // R = Linv^T @ T:               k in [max(I0,J0), 256)
    k_bmm<1, 0><<<dim3(HO, 2, 2), 256, 0, stream>>>(LINV, (long)O_ * M2 * M2, (long)M2 * M2, M2,
                                                    Tb, (long)O_ * M2 * M2, (long)M2 * M2, M2,
                                                    Rb, (long)O_ * M2 * M2, (long)M2 * M2, M2, M2, 3, 0, 1.f, 0);
    // G = Linv^T @ Linv
    k_bmm<1, 0><<<dim3(HO, 2, 2), 256, 0, stream>>>(LINV, (long)O_ * M2 * M2, (long)M2 * M2, M2,
                                                    LINV, (long)O_ * M2 * M2, (long)M2 * M2, M2,
                                                    Gb, (long)O_ * M2 * M2, (long)M2 * M2, M2, M2, 3, 0, 1.f, 0);
    // G -= R @ R^T
    k_bmm<0, 1><<<dim3(HO, 2, 2), 256, 0, stream>>>(Rb, (long)O_ * M2 * M2, (long)M2 * M2, M2,
                                                    Rb, (long)O_ * M2 * M2, (long)M2 * M2, M2,
                                                    Gb, (long)O_ * M2 * M2, (long)M2 * M2, M2, M2, 0, 0, -1.f, 1);

    k_kb2<<<dim3(16, HO), 256, 0, stream>>>(ZS, ZN, XS, XN, SF2v, Gb, CV, (float*)d_out);
}

// Round 2
// 2327.130 us; speedup vs baseline: 1.3190x; 1.3190x over previous
//
#include <hip/hip_runtime.h>

#define H_ 4
#define O_ 32
#define HO 128
#define M_ 128
#define M2 256
#define D_ 16
#define B_ 1024
#define JIT 1e-4f

// ---------------------------------------------------------------------------
// prep: inverse lengthscales and sf2
__global__ void k_prep(const float* __restrict__ theta, float* __restrict__ LSI,
                       float* __restrict__ SF2) {
    int t = threadIdx.x;  // 64 threads
    if (t < H_ * D_) {
        int h = t / D_, d = t % D_;
        LSI[h * D_ + d] = __expf(-theta[h * (D_ + 1) + 1 + d]);
    }
    if (t < H_) SF2[t] = __expf(theta[t * (D_ + 1)]);
}

// scaled x rows + squared norms
__global__ void k_scale_x(const float* __restrict__ x, const float* __restrict__ LSI,
                          float* __restrict__ XS, float* __restrict__ XN) {
    int idx = blockIdx.x * 256 + threadIdx.x;  // h*B + b
    if (idx >= H_ * B_) return;
    int h = idx / B_, b = idx % B_;
    float s = 0.f;
#pragma unroll
    for (int d = 0; d < D_; d++) {
        float v = x[b * D_ + d] * LSI[h * D_ + d];
        XS[(long)idx * D_ + d] = v;
        s += v * v;
    }
    XN[idx] = s;
}

// scaled z_joint rows + squared norms ([z_old; z] per o, per h)
__global__ void k_scale_z(const float* __restrict__ z, const float* __restrict__ z_old,
                          const float* __restrict__ LSI, float* __restrict__ ZS,
                          float* __restrict__ ZN) {
    int idx = blockIdx.x * 256 + threadIdx.x;  // (h*O+o)*256 + i
    int i = idx & 255;
    int pair = idx >> 8;
    int h = pair >> 5, o = pair & 31;
    const float* src = (i < M_) ? (z_old + ((long)o * M_ + i) * D_)
                                : (z + ((long)o * M_ + (i - M_)) * D_);
    float s = 0.f;
#pragma unroll
    for (int d = 0; d < D_; d++) {
        float v = src[d] * LSI[h * D_ + d];
        ZS[(long)idx * D_ + d] = v;
        s += v * v;
    }
    ZN[idx] = s;
}

// unpack packed tril vec -> dense lower [O][128][128]
__global__ void k_unpack(const float* __restrict__ vec, float* __restrict__ UT) {
    long idx = (long)blockIdx.x * 256 + threadIdx.x;
    int o = (int)(idx >> 14);
    int e = (int)(idx & 16383);
    int i = e >> 7, j = e & 127;
    float v = (j <= i) ? vec[(long)o * (M_ * (M_ + 1) / 2) + i * (i + 1) / 2 + j] : 0.f;
    UT[idx] = v;
}

// kuu2 = k_rbf(z_joint, z_joint) + JIT*I   [HO][256][256]
__global__ __launch_bounds__(256) void k_kuu2(const float* __restrict__ ZS,
                                              const float* __restrict__ ZN,
                                              const float* __restrict__ SF2,
                                              float* __restrict__ K2) {
    int pair = blockIdx.x;
    int h = pair >> 5;
    int t = threadIdx.x;
    __shared__ float zs[M2][D_];
    __shared__ float zn[M2];
    for (int e = t; e < M2 * D_; e += 256) zs[e / D_][e % D_] = ZS[(long)pair * M2 * D_ + e];
    zn[t] = ZN[pair * M2 + t];
    __syncthreads();
    float sf2 = SF2[h];
    float my[D_];
#pragma unroll
    for (int d = 0; d < D_; d++) my[d] = zs[t][d];
    float myn = zn[t];
    for (int q = 0; q < M2; q++) {
        float dot = 0.f;
#pragma unroll
        for (int d = 0; d < D_; d++) dot += zs[q][d] * my[d];
        float d2 = fmaxf(zn[q] + myn - 2.f * dot, 0.f);
        float v = sf2 * __expf(-0.5f * d2);
        if (q == t) v += JIT;
        K2[(long)pair * M2 * M2 + (long)q * M2 + t] = v;
    }
}

// in-LDS packed Cholesky of a 128x128 block (parametrized src/dst layout);
// writes dense lower, zeros upper of the 128x128 destination block.
__global__ __launch_bounds__(128) void k_chol128(const float* __restrict__ src, long sps, int ldsrc,
                                                 float* __restrict__ dst, long spd, int lddst) {
    int pair = blockIdx.x, t = threadIdx.x;
    __shared__ float Ap[M_ * (M_ + 1) / 2];
    const float* S = src + (long)pair * sps;
    for (int e = t; e < M_ * (M_ + 1) / 2; e += 128) {
        int i = (int)((sqrtf(8.f * e + 1.f) - 1.f) * 0.5f);
        while ((i + 1) * (i + 2) / 2 <= e) i++;
        while (i * (i + 1) / 2 > e) i--;
        int j = e - i * (i + 1) / 2;
        Ap[e] = S[(long)i * ldsrc + j];
    }
    __syncthreads();
    for (int k = 0; k < M_; k++) {
        float s = sqrtf(Ap[k * (k + 1) / 2 + k]);
        float rinv = 1.f / s;
        __syncthreads();
        int i = k + 1 + t;
        float aik = 0.f;
        if (i < M_) {
            aik = Ap[i * (i + 1) / 2 + k] * rinv;
            Ap[i * (i + 1) / 2 + k] = aik;
        }
        if (t == 0) Ap[k * (k + 1) / 2 + k] = s;
        __syncthreads();
        if (i < M_) {
            for (int j = k + 1; j <= i; j++) Ap[i * (i + 1) / 2 + j] -= aik * Ap[j * (j + 1) / 2 + k];
        }
        __syncthreads();
    }
    float* Dst = dst + (long)pair * spd;
    for (int e = t; e < M_ * M_; e += 128) {
        int i = e >> 7, j = e & 127;
        Dst[(long)i * lddst + j] = (j <= i) ? Ap[i * (i + 1) / 2 + j] : 0.f;
    }
}

// transpose A1 [pair][128][128] into BL quadrant of L256 [pair][256][256]
__global__ __launch_bounds__(256) void k_copyT(const float* __restrict__ A1, float* __restrict__ L) {
    int pair = blockIdx.x, t = threadIdx.x;
    int tx = t & 31, ty = t >> 5;  // 8 rows of 32
    __shared__ float tl[32][33];
    for (int bi = 0; bi < 4; bi++)
        for (int bj = 0; bj < 4; bj++) {
            for (int r = ty; r < 32; r += 8)
                tl[r][tx] = A1[(long)pair * 16384 + (long)(bj * 32 + r) * 128 + bi * 32 + tx];
            __syncthreads();
            for (int r = ty; r < 32; r += 8)
                L[(long)pair * 65536 + (long)(128 + bi * 32 + r) * 256 + bj * 32 + tx] = tl[tx][r];
            __syncthreads();
        }
}

// invert 64x64 lower-tri diagonal blocks: grid (nPair, NB), 64 threads
__global__ __launch_bounds__(64) void k_diaginv(const float* __restrict__ L, long sPair, int ld,
                                                float* __restrict__ Out, long sPairO, int ldo) {
    int pair = blockIdx.x, I0 = blockIdx.y * 64;
    int c = threadIdx.x;
    __shared__ float Ld[64][66];
    __shared__ float Wd[64][66];
    const float* Lp = L + (long)pair * sPair + (long)I0 * ld + I0;
    for (int e = c; e < 4096; e += 64) {
        int i = e >> 6, j = e & 63;
        Ld[i][j] = Lp[(long)i * ld + j];
    }
    __syncthreads();
    for (int i = 0; i < 64; i++) {
        float acc = (i == c) ? 1.f : 0.f;
        for (int j = 0; j < i; j++) acc -= Ld[i][j] * Wd[j][c];
        Wd[i][c] = acc / Ld[i][i];
    }
    float* Op = Out + (long)pair * sPairO + (long)I0 * ldo + I0;
    for (int i = 0; i < 64; i++) Op[(long)i * ldo + c] = Wd[i][c];
}

// off-diagonal blocks of triangular inverse: Linv_IJ = -Dinv_I * sum_{K=J..I-1} L_IK Linv_KJ
__global__ __launch_bounds__(256) void k_linvoff(const float* __restrict__ L, long sPair, int ld,
                                                 float* __restrict__ Linv, long sPairO, int ldo,
                                                 int d) {
    int pair = blockIdx.x, J = blockIdx.y, I = J + d;
    int I0 = I * 64, J0 = J * 64;
    int t = threadIdx.x, tx = t & 15, ty = t >> 4;
    __shared__ float La[64][66], Lb[64][66], Ss[64][66];
    float acc[4][4] = {};
    for (int K = J; K < I; K++) {
        int K0 = K * 64;
        for (int e = t; e < 4096; e += 256) {
            int i = e >> 6, k = e & 63;
            La[i][k] = L[(long)pair * sPair + (long)(I0 + i) * ld + K0 + k];
            Lb[i][k] = Linv[(long)pair * sPairO + (long)(K0 + i) * ldo + J0 + k];
        }
        __syncthreads();
#pragma unroll 4
        for (int kk = 0; kk < 64; kk++) {
            float a[4], b[4];
#pragma unroll
            for (int q = 0; q < 4; q++) { a[q] = La[ty + 16 * q][kk]; b[q] = Lb[kk][tx + 16 * q]; }
#pragma unroll
            for (int q = 0; q < 4; q++)
#pragma unroll
                for (int r = 0; r < 4; r++) acc[q][r] += a[q] * b[r];
        }
        __syncthreads();
    }
#pragma unroll
    for (int q = 0; q < 4; q++)
#pragma unroll
        for (int r = 0; r < 4; r++) Ss[ty + 16 * q][tx + 16 * r] = acc[q][r];
    for (int e = t; e < 4096; e += 256) {
        int i = e >> 6, k = e & 63;
        La[i][k] = Linv[(long)pair * sPairO + (long)(I0 + i) * ldo + I0 + k];
    }
    __syncthreads();
    float out[4][4] = {};
#pragma unroll 4
    for (int kk = 0; kk < 64; kk++) {
        float a[4], b[4];
#pragma unroll
        for (int q = 0; q < 4; q++) { a[q] = La[ty + 16 * q][kk]; b[q] = Ss[kk][tx + 16 * q]; }
#pragma unroll
        for (int q = 0; q < 4; q++)
#pragma unroll
            for (int r = 0; r < 4; r++) out[q][r] += a[q] * b[r];
    }
#pragma unroll
    for (int q = 0; q < 4; q++)
#pragma unroll
        for (int r = 0; r < 4; r++)
            Linv[(long)pair * sPairO + (long)(I0 + ty + 16 * q) * ldo + J0 + tx + 16 * r] = -out[q][r];
}

// a2 = Linv128 * m_old ; m_new = A1^T a2 + u_mean ; write m_joint
__global__ __launch_bounds__(128) void k_stage1vec(const float* __restrict__ Linv128,
                                                   const float* __restrict__ A1,
                                                   const float* __restrict__ m_old,
                                                   const float* __restrict__ u_mean,
                                                   float* __restrict__ MJ) {
    int pair = blockIdx.x, o = pair & 31, t = threadIdx.x;
    __shared__ float mo[128], a2[128];
    mo[t] = m_old[o * 128 + t];
    __syncthreads();
    const float* Lr = Linv128 + (long)pair * 16384 + (long)t * 128;
    float acc = 0.f;
    for (int j = 0; j <= t; j++) acc += Lr[j] * mo[j];
    a2[t] = acc;
    __syncthreads();
    float m = 0.f;
    for (int i = 0; i < 128; i++) m += A1[(long)pair * 16384 + (long)i * 128 + t] * a2[i];
    MJ[pair * 256 + t] = mo[t];
    MJ[pair * 256 + 128 + t] = m + u_mean[o * 128 + t];
}

// assemble COVj = cov_joint + JIT*I
__global__ __launch_bounds__(256) void k_assemble(const float* __restrict__ SOLD,
                                                  const float* __restrict__ SCUR,
                                                  const float* __restrict__ TRb,
                                                  const float* __restrict__ BRb,
                                                  float* __restrict__ COV) {
    int pair = blockIdx.x, quad = blockIdx.y, o = pair & 31, t = threadIdx.x;
    long base = (long)pair * M2 * M2;
    for (int e = t; e < 16384; e += 256) {
        int i = e >> 7, j = e & 127;
        if (quad == 0) {
            COV[base + (long)i * 256 + j] = SOLD[(long)o * 16384 + e] + ((i == j) ? JIT : 0.f);
        } else if (quad == 1) {
            COV[base + (long)i * 256 + 128 + j] = TRb[(long)pair * 16384 + e];
        } else if (quad == 2) {
            COV[base + (long)(128 + i) * 256 + j] = TRb[(long)pair * 16384 + (long)j * 128 + i];
        } else {
            COV[base + (long)(128 + i) * 256 + 128 + j] =
                SCUR[(long)o * 16384 + e] + BRb[(long)pair * 16384 + e] + ((i == j) ? JIT : 0.f);
        }
    }
}

// c = Linv^T (Linv * m_joint)
__global__ __launch_bounds__(256) void k_cvec(const float* __restrict__ Linv,
                                              const float* __restrict__ MJ,
                                              float* __restrict__ CV) {
    int pair = blockIdx.x, t = threadIdx.x;
    __shared__ float mj[256], tmp[256];
    mj[t] = MJ[pair * 256 + t];
    __syncthreads();
    const float* Lp = Linv + (long)pair * 65536;
    float acc = 0.f;
    for (int j = 0; j <= t; j++) acc += Lp[(long)t * 256 + j] * mj[j];
    tmp[t] = acc;
    __syncthreads();
    float c = 0.f;
    for (int k = t; k < 256; k++) c += Lp[(long)k * 256 + t] * tmp[k];
    CV[pair * 256 + t] = c;
}

// generic batched SGEMM: C = alpha * opA(A) * opB(B) (+C if accum==1; +Dm if accum==2)
// tiles3: blockIdx.y in {0,1,2} -> (I0,J0) in {(0,0),(128,128),(128,0)+mirror}
template <int TA, int TB>
__global__ __launch_bounds__(256) void k_bmm(const float* __restrict__ A, long aSH, long aSO, int lda,
                                             const float* __restrict__ B, long bSH, long bSO, int ldb,
                                             float* __restrict__ C, long cSH, long cSO, int ldc,
                                             const float* __restrict__ Dm,
                                             int Ksz, int kLoMode, int kHiMode, float alpha,
                                             int accum, int tiles3) {
    int pair = blockIdx.x;
    int h = pair >> 5, o = pair & 31;
    const float* Ap = A + (long)h * aSH + (long)o * aSO;
    const float* Bp = B + (long)h * bSH + (long)o * bSO;
    float* Cp = C + (long)h * cSH + (long)o * cSO;
    const float* Dp = Dm ? (Dm + (long)h * cSH + (long)o * cSO) : nullptr;
    int I0, J0, mir = 0;
    if (tiles3) {
        int qb = blockIdx.y;
        I0 = (qb == 0) ? 0 : 128;
        J0 = (qb == 2) ? 0 : I0;
        mir = (qb == 2);
    } else {
        I0 = blockIdx.y * 128;
        J0 = blockIdx.z * 128;
    }
    int k0 = (kLoMode == 0) ? 0 : (kLoMode == 1) ? I0 : (kLoMode == 2) ? J0 : max(I0, J0);
    int k1 = (kHiMode == 0) ? Ksz : (kHiMode == 1) ? min(Ksz, I0 + 128) : min(Ksz, min(I0, J0) + 128);
    int t = threadIdx.x, tx = t & 15, ty = t >> 4;
    __shared__ float As[16][132], Bs[16][132];
    float acc[8][8] = {};
    for (int kt = k0; kt < k1; kt += 16) {
#pragma unroll
        for (int q = 0; q < 8; q++) {
            int e = q * 256 + t;
            if (TA) {
                int kk = e >> 7, m = e & 127;
                As[kk][m] = Ap[(long)(kt + kk) * lda + I0 + m];
            } else {
                int m = e >> 4, kk = e & 15;
                As[kk][m] = Ap[(long)(I0 + m) * lda + kt + kk];
            }
            if (TB) {
                int n = e >> 4, kk = e & 15;
                Bs[kk][n] = Bp[(long)(J0 + n) * ldb + kt + kk];
            } else {
                int kk = e >> 7, n = e & 127;
                Bs[kk][n] = Bp[(long)(kt + kk) * ldb + J0 + n];
            }
        }
        __syncthreads();
#pragma unroll
        for (int kk = 0; kk < 16; kk++) {
            float a[8], b[8];
#pragma unroll
            for (int q = 0; q < 8; q++) { a[q] = As[kk][ty + 16 * q]; b[q] = Bs[kk][tx + 16 * q]; }
#pragma unroll
            for (int q = 0; q < 8; q++)
#pragma unroll
                for (int r = 0; r < 8; r++) acc[q][r] += a[q] * b[r];
        }
        __syncthreads();
    }
#pragma unroll
    for (int q = 0; q < 8; q++)
#pragma unroll
        for (int r = 0; r < 8; r++) {
            int row = I0 + ty + 16 * q, col = J0 + tx + 16 * r;
            long idx = (long)row * ldc + col;
            float v = alpha * acc[q][r];
            if (accum == 1) v += Cp[idx];
            if (accum == 2) v += Dp[idx];
            Cp[idx] = v;
            if (mir) Cp[(long)col * ldc + row] = v;
        }
}

// fused final kernel: per (pair, 64-col b-tile): build K tile in LDS,
// q[b] = K^T G K (diag), mu[b] = K^T c, var = sf2 - q
__global__ __launch_bounds__(256) void k_kb2(const float* __restrict__ ZS, const float* __restrict__ ZN,
                                             const float* __restrict__ XS, const float* __restrict__ XN,
                                             const float* __restrict__ SF2, const float* __restrict__ G,
                                             const float* __restrict__ CV, float* __restrict__ out) {
    int btile = blockIdx.x;  // 16
    int pair = blockIdx.y;   // 128
    int h = pair >> 5;
    int t = threadIdx.x;
    int c = t & 63;
    int r = __builtin_amdgcn_readfirstlane(t >> 6);  // wave id, force SGPR
    int b = btile * 64 + c;
    __shared__ float Ks[256][64];  // exactly 64 KB
    float xs[16];
#pragma unroll
    for (int d = 0; d < 16; d++) xs[d] = XS[((long)h * B_ + b) * 16 + d];
    float xn = XN[h * B_ + b];
    float sf2 = SF2[h];
    const float* zsp = ZS + (long)pair * 256 * 16;
    const float* znp = ZN + pair * 256;
    for (int i = r * 64; i < r * 64 + 64; i++) {
        float dot = 0.f;
#pragma unroll
        for (int d = 0; d < 16; d++) dot += zsp[(long)i * 16 + d] * xs[d];
        float d2 = fmaxf(znp[i] + xn - 2.f * dot, 0.f);
        Ks[i][c] = sf2 * __expf(-0.5f * d2);
    }
    __syncthreads();
    const float* Gp = G + (long)pair * 65536;
    const float* cvp = CV + pair * 256;
    float qacc = 0.f, macc = 0.f;
    for (int i4 = 0; i4 < 16; i4++) {
        int i0 = r * 64 + i4 * 4;
        float y0 = 0.f, y1 = 0.f, y2 = 0.f, y3 = 0.f;
        const float* g0 = Gp + (long)i0 * 256;
        const float* g1 = g0 + 256;
        const float* g2 = g0 + 512;
        const float* g3 = g0 + 768;
#pragma unroll 4
        for (int j = 0; j < 256; j++) {
            float kv = Ks[j][c];
            y0 += g0[j] * kv;
            y1 += g1[j] * kv;
            y2 += g2[j] * kv;
            y3 += g3[j] * kv;
        }
        qacc += Ks[i0][c] * y0 + Ks[i0 + 1][c] * y1 + Ks[i0 + 2][c] * y2 + Ks[i0 + 3][c] * y3;
        macc += Ks[i0][c] * cvp[i0] + Ks[i0 + 1][c] * cvp[i0 + 1] + Ks[i0 + 2][c] * cvp[i0 + 2] +
                Ks[i0 + 3][c] * cvp[i0 + 3];
    }
    __syncthreads();  // done reading Ks; reuse as reduction buffer
    float* red = &Ks[0][0];
    red[r * 64 + c] = qacc;
    red[256 + r * 64 + c] = macc;
    __syncthreads();
    if (t < 64) {
        float q = red[t] + red[64 + t] + red[128 + t] + red[192 + t];
        float m = red[256 + t] + red[320 + t] + red[384 + t] + red[448 + t];
        long ob = (long)pair * 1024 + btile * 64 + t;
        out[ob] = m;
        out[(long)H_ * O_ * B_ + ob] = sf2 - q;
    }
}

// ---------------------------------------------------------------------------
extern "C" void kernel_launch(void* const* d_in, const int* in_sizes, int n_in,
                              void* d_out, int out_size, void* d_ws, size_t ws_size,
                              hipStream_t stream) {
    const float* x = (const float*)d_in[0];
    const float* z = (const float*)d_in[1];
    const float* u_mean = (const float*)d_in[2];
    const float* u_tril_vec = (const float*)d_in[3];
    const float* m_old = (const float*)d_in[4];
    const float* L_old = (const float*)d_in[5];
    const float* z_old = (const float*)d_in[6];
    const float* theta = (const float*)d_in[7];

    const long BIGSZ = (long)HO * M2 * M2;  // 8388608
    const long MSZ = (long)HO * M_ * M_;    // 2097152
    const long OSZ = (long)O_ * M_ * M_;    // 524288
    const long SH2 = (long)O_ * M2 * M2;    // per-h stride of big arrays
    const long SO2 = (long)M2 * M2;
    const long SH1 = (long)O_ * M_ * M_;
    const long SO1 = (long)M_ * M_;

    float* ws = (float*)d_ws;
    long off = 0;
    float* BIG0 = ws + off; off += BIGSZ;  // KUU2 -> AINV
    float* BIG1 = ws + off; off += BIGSZ;  // UT -> COVj -> G
    float* BIG2 = ws + off; off += BIGSZ;  // Linv128|A1|A3|ATX (then TRb,BRb) -> LINV
    float* BIG3 = ws + off; off += BIGSZ;  // L256 -> P
    float* SOLD = ws + off; off += OSZ;
    float* SCUR = ws + off; off += OSZ;
    float* ZS = ws + off; off += (long)HO * M2 * D_;
    float* XS = ws + off; off += (long)H_ * B_ * D_;
    float* ZN = ws + off; off += (long)HO * M2;
    float* XN = ws + off; off += (long)H_ * B_;
    float* MJ = ws + off; off += (long)HO * M2;
    float* CV = ws + off; off += (long)HO * M2;
    float* LSI = ws + off; off += H_ * D_;
    float* SF2v = ws + off; off += H_;

    float* UT = BIG1;
    float* KUU2 = BIG0;
    float* COV = BIG1;
    float* Linv128 = BIG2;            // slot 0
    float* A1 = BIG2 + MSZ;           // slot 1
    float* A3 = BIG2 + 2 * MSZ;       // slot 2
    float* ATX = BIG2 + 3 * MSZ;      // slot 3
    float* TRb = BIG2 + 2 * MSZ;      // reuse slot 2 (A3 dead)
    float* BRb = BIG2;                // reuse slot 0 (Linv128 dead)
    float* L256 = BIG3;
    float* LINV = BIG2;
    float* AINV = BIG0;
    float* Pb = BIG3;
    float* Gb = BIG1;
    const long BRoff = 128L * M2 + 128;  // BR quadrant offset in a 256x256

    k_prep<<<1, 64, 0, stream>>>(theta, LSI, SF2v);
    k_scale_x<<<(H_ * B_ + 255) / 256, 256, 0, stream>>>(x, LSI, XS, XN);
    k_scale_z<<<HO * M2 / 256, 256, 0, stream>>>(z, z_old, LSI, ZS, ZN);
    k_unpack<<<(int)(OSZ / 256), 256, 0, stream>>>(u_tril_vec, UT);

    // S_old = L_old L_old^T ; S_cur = UT UT^T   (batched over o)
    k_bmm<0, 1><<<dim3(O_, 1, 1), 256, 0, stream>>>(L_old, 0, SO1, M_, L_old, 0, SO1, M_,
                                                    SOLD, 0, SO1, M_, nullptr, M_, 0, 0, 1.f, 0, 0);
    k_bmm<0, 1><<<dim3(O_, 1, 1), 256, 0, stream>>>(UT, 0, SO1, M_, UT, 0, SO1, M_,
                                                    SCUR, 0, SO1, M_, nullptr, M_, 0, 0, 1.f, 0, 0);

    k_kuu2<<<HO, 256, 0, stream>>>(ZS, ZN, SF2v, KUU2);
    // chol of TL 128x128 -> L256 TL
    k_chol128<<<HO, 128, 0, stream>>>(KUU2, SO2, M2, L256, SO2, M2);

    hipMemsetAsync(Linv128, 0, MSZ * sizeof(float), stream);
    k_diaginv<<<dim3(HO, 2), 64, 0, stream>>>(L256, SO2, M2, Linv128, SO1, M_);
    k_linvoff<<<dim3(HO, 1), 256, 0, stream>>>(L256, SO2, M2, Linv128, SO1, M_, 1);

    // A1 = Linv128 @ kuf (kuf = KUU2 rows 0..127, cols 128..255)
    k_bmm<0, 0><<<dim3(HO, 1, 1), 256, 0, stream>>>(Linv128, SH1, SO1, M_,
                                                    KUU2 + 128, SH2, SO2, M2,
                                                    A1, SH1, SO1, M_, nullptr, M_, 0, 0, 1.f, 0, 0);
    // A3 = Linv128 @ L_old
    k_bmm<0, 0><<<dim3(HO, 1, 1), 256, 0, stream>>>(Linv128, SH1, SO1, M_, L_old, 0, SO1, M_,
                                                    A3, SH1, SO1, M_, nullptr, M_, 0, 0, 1.f, 0, 0);
    k_stage1vec<<<HO, 128, 0, stream>>>(Linv128, A1, m_old, u_mean, MJ);

    // ATX = A3^T @ A1
    k_bmm<1, 0><<<dim3(HO, 1, 1), 256, 0, stream>>>(A3, SH1, SO1, M_, A1, SH1, SO1, M_,
                                                    ATX, SH1, SO1, M_, nullptr, M_, 0, 0, 1.f, 0, 0);
    // TRb = L_old @ ATX   (overwrites A3 slot — A3 dead)
    k_bmm<0, 0><<<dim3(HO, 1, 1), 256, 0, stream>>>(L_old, 0, SO1, M_, ATX, SH1, SO1, M_,
                                                    TRb, SH1, SO1, M_, nullptr, M_, 0, 0, 1.f, 0, 0);
    // BRb = ATX^T @ ATX   (overwrites Linv128 slot — dead after stage1vec/A1/A3)
    k_bmm<1, 0><<<dim3(HO, 1, 1), 256, 0, stream>>>(ATX, SH1, SO1, M_, ATX, SH1, SO1, M_,
                                                    BRb, SH1, SO1, M_, nullptr, M_, 0, 0, 1.f, 0, 0);

    k_assemble<<<dim3(HO, 4), 256, 0, stream>>>(SOLD, SCUR, TRb, BRb, COV);

    // L256 BL = A1^T
    k_copyT<<<HO, 256, 0, stream>>>(A1, L256);
    // Schur: KUU2_BR -= A1^T A1
    k_bmm<1, 0><<<dim3(HO, 1, 1), 256, 0, stream>>>(A1, SH1, SO1, M_, A1, SH1, SO1, M_,
                                                    KUU2 + BRoff, SH2, SO2, M2, nullptr,
                                                    M_, 0, 0, -1.f, 1, 0);
    // L22 = chol(S22) -> L256 BR
    k_chol128<<<HO, 128, 0, stream>>>(KUU2 + BRoff, SO2, M2, L256 + BRoff, SO2, M2);

    // LINV = L256^{-1}  (overwrites all of BIG2; A1/TRb/BRb consumed above)
    hipMemsetAsync(LINV, 0, BIGSZ * sizeof(float), stream);
    k_diaginv<<<dim3(HO, 4), 64, 0, stream>>>(L256, SO2, M2, LINV, SO2, M2);
    k_linvoff<<<dim3(HO, 3), 256, 0, stream>>>(L256, SO2, M2, LINV, SO2, M2, 1);
    k_linvoff<<<dim3(HO, 2), 256, 0, stream>>>(L256, SO2, M2, LINV, SO2, M2, 2);
    k_linvoff<<<dim3(HO, 1), 256, 0, stream>>>(L256, SO2, M2, LINV, SO2, M2, 3);

    k_cvec<<<HO, 256, 0, stream>>>(LINV, MJ, CV);

    // AINV = LINV^T @ LINV  (symmetric: 3 tiles + mirror; k >= max(I0,J0))
    k_bmm<1, 0><<<dim3(HO, 3, 1), 256, 0, stream>>>(LINV, SH2, SO2, M2, LINV, SH2, SO2, M2,
                                                    AINV, SH2, SO2, M2, nullptr,
                                                    M2, 3, 0, 1.f, 0, 1);
    // P = COVj @ AINV  (L256 dead -> BIG3)
    k_bmm<0, 0><<<dim3(HO, 2, 2), 256, 0, stream>>>(COV, SH2, SO2, M2, AINV, SH2, SO2, M2,
                                                    Pb, SH2, SO2, M2, nullptr,
                                                    M2, 0, 0, 1.f, 0, 0);
    // G = AINV - P^T @ AINV  (symmetric: 3 tiles + mirror; COVj dead -> BIG1)
    k_bmm<1, 0><<<dim3(HO, 3, 1), 256, 0, stream>>>(Pb, SH2, SO2, M2, AINV, SH2, SO2, M2,
                                                    Gb, SH2, SO2, M2, AINV,
                                                    M2, 0, 0, -1.f, 2, 1);

    k_kb2<<<dim3(16, HO), 256, 0, stream>>>(ZS, ZN, XS, XN, SF2v, Gb, CV, (float*)d_out);
}

// Round 3
// 1726.138 us; speedup vs baseline: 1.7783x; 1.3482x over previous
//
#include <hip/hip_runtime.h>

#define H_ 4
#define O_ 32
#define HO 128
#define M_ 128
#define M2 256
#define D_ 16
#define B_ 1024
#define JIT 1e-4f

typedef unsigned short ushort_t;
typedef __bf16 v8bf __attribute__((ext_vector_type(8)));
typedef float v16f __attribute__((ext_vector_type(16)));
typedef unsigned short v8us __attribute__((ext_vector_type(8)));
typedef unsigned short v4us __attribute__((ext_vector_type(4)));

// ---------------------------------------------------------------------------
// prep: inverse lengthscales and sf2
__global__ void k_prep(const float* __restrict__ theta, float* __restrict__ LSI,
                       float* __restrict__ SF2) {
    int t = threadIdx.x;  // 64 threads
    if (t < H_ * D_) {
        int h = t / D_, d = t % D_;
        LSI[h * D_ + d] = __expf(-theta[h * (D_ + 1) + 1 + d]);
    }
    if (t < H_) SF2[t] = __expf(theta[t * (D_ + 1)]);
}

// scaled x rows + squared norms
__global__ void k_scale_x(const float* __restrict__ x, const float* __restrict__ LSI,
                          float* __restrict__ XS, float* __restrict__ XN) {
    int idx = blockIdx.x * 256 + threadIdx.x;  // h*B + b
    if (idx >= H_ * B_) return;
    int h = idx / B_, b = idx % B_;
    float s = 0.f;
#pragma unroll
    for (int d = 0; d < D_; d++) {
        float v = x[b * D_ + d] * LSI[h * D_ + d];
        XS[(long)idx * D_ + d] = v;
        s += v * v;
    }
    XN[idx] = s;
}

// scaled z_joint rows + squared norms ([z_old; z] per o, per h)
__global__ void k_scale_z(const float* __restrict__ z, const float* __restrict__ z_old,
                          const float* __restrict__ LSI, float* __restrict__ ZS,
                          float* __restrict__ ZN) {
    int idx = blockIdx.x * 256 + threadIdx.x;  // (h*O+o)*256 + i
    int i = idx & 255;
    int pair = idx >> 8;
    int h = pair >> 5, o = pair & 31;
    const float* src = (i < M_) ? (z_old + ((long)o * M_ + i) * D_)
                                : (z + ((long)o * M_ + (i - M_)) * D_);
    float s = 0.f;
#pragma unroll
    for (int d = 0; d < D_; d++) {
        float v = src[d] * LSI[h * D_ + d];
        ZS[(long)idx * D_ + d] = v;
        s += v * v;
    }
    ZN[idx] = s;
}

// unpack packed tril vec -> dense lower [O][128][128]
__global__ void k_unpack(const float* __restrict__ vec, float* __restrict__ UT) {
    long idx = (long)blockIdx.x * 256 + threadIdx.x;
    int o = (int)(idx >> 14);
    int e = (int)(idx & 16383);
    int i = e >> 7, j = e & 127;
    float v = (j <= i) ? vec[(long)o * (M_ * (M_ + 1) / 2) + i * (i + 1) / 2 + j] : 0.f;
    UT[idx] = v;
}

// kuu2 = k_rbf(z_joint, z_joint) + JIT*I   [HO][256][256]
__global__ __launch_bounds__(256) void k_kuu2(const float* __restrict__ ZS,
                                              const float* __restrict__ ZN,
                                              const float* __restrict__ SF2,
                                              float* __restrict__ K2) {
    int pair = blockIdx.x;
    int h = pair >> 5;
    int t = threadIdx.x;
    __shared__ float zs[M2][D_];
    __shared__ float zn[M2];
    for (int e = t; e < M2 * D_; e += 256) zs[e / D_][e % D_] = ZS[(long)pair * M2 * D_ + e];
    zn[t] = ZN[pair * M2 + t];
    __syncthreads();
    float sf2 = SF2[h];
    float my[D_];
#pragma unroll
    for (int d = 0; d < D_; d++) my[d] = zs[t][d];
    float myn = zn[t];
    for (int q = 0; q < M2; q++) {
        float dot = 0.f;
#pragma unroll
        for (int d = 0; d < D_; d++) dot += zs[q][d] * my[d];
        float d2 = fmaxf(zn[q] + myn - 2.f * dot, 0.f);
        float v = sf2 * __expf(-0.5f * d2);
        if (q == t) v += JIT;
        K2[(long)pair * M2 * M2 + (long)q * M2 + t] = v;
    }
}

// in-LDS packed Cholesky of a 128x128 block (parametrized src/dst layout);
// writes dense lower, zeros upper of the 128x128 destination block.
__global__ __launch_bounds__(128) void k_chol128(const float* __restrict__ src, long sps, int ldsrc,
                                                 float* __restrict__ dst, long spd, int lddst) {
    int pair = blockIdx.x, t = threadIdx.x;
    __shared__ float Ap[M_ * (M_ + 1) / 2];
    const float* S = src + (long)pair * sps;
    for (int e = t; e < M_ * (M_ + 1) / 2; e += 128) {
        int i = (int)((sqrtf(8.f * e + 1.f) - 1.f) * 0.5f);
        while ((i + 1) * (i + 2) / 2 <= e) i++;
        while (i * (i + 1) / 2 > e) i--;
        int j = e - i * (i + 1) / 2;
        Ap[e] = S[(long)i * ldsrc + j];
    }
    __syncthreads();
    for (int k = 0; k < M_; k++) {
        float s = sqrtf(Ap[k * (k + 1) / 2 + k]);
        float rinv = 1.f / s;
        __syncthreads();
        int i = k + 1 + t;
        float aik = 0.f;
        if (i < M_) {
            aik = Ap[i * (i + 1) / 2 + k] * rinv;
            Ap[i * (i + 1) / 2 + k] = aik;
        }
        if (t == 0) Ap[k * (k + 1) / 2 + k] = s;
        __syncthreads();
        if (i < M_) {
            for (int j = k + 1; j <= i; j++) Ap[i * (i + 1) / 2 + j] -= aik * Ap[j * (j + 1) / 2 + k];
        }
        __syncthreads();
    }
    float* Dst = dst + (long)pair * spd;
    for (int e = t; e < M_ * M_; e += 128) {
        int i = e >> 7, j = e & 127;
        Dst[(long)i * lddst + j] = (j <= i) ? Ap[i * (i + 1) / 2 + j] : 0.f;
    }
}

// transpose A1 [pair][128][128] into BL quadrant of L256 [pair][256][256]
__global__ __launch_bounds__(256) void k_copyT(const float* __restrict__ A1, float* __restrict__ L) {
    int pair = blockIdx.x, t = threadIdx.x;
    int tx = t & 31, ty = t >> 5;  // 8 rows of 32
    __shared__ float tl[32][33];
    for (int bi = 0; bi < 4; bi++)
        for (int bj = 0; bj < 4; bj++) {
            for (int r = ty; r < 32; r += 8)
                tl[r][tx] = A1[(long)pair * 16384 + (long)(bj * 32 + r) * 128 + bi * 32 + tx];
            __syncthreads();
            for (int r = ty; r < 32; r += 8)
                L[(long)pair * 65536 + (long)(128 + bi * 32 + r) * 256 + bj * 32 + tx] = tl[tx][r];
            __syncthreads();
        }
}

// invert 64x64 lower-tri diagonal blocks: grid (nPair, NB), 64 threads
__global__ __launch_bounds__(64) void k_diaginv(const float* __restrict__ L, long sPair, int ld,
                                                float* __restrict__ Out, long sPairO, int ldo) {
    int pair = blockIdx.x, I0 = blockIdx.y * 64;
    int c = threadIdx.x;
    __shared__ float Ld[64][66];
    __shared__ float Wd[64][66];
    const float* Lp = L + (long)pair * sPair + (long)I0 * ld + I0;
    for (int e = c; e < 4096; e += 64) {
        int i = e >> 6, j = e & 63;
        Ld[i][j] = Lp[(long)i * ld + j];
    }
    __syncthreads();
    for (int i = 0; i < 64; i++) {
        float acc = (i == c) ? 1.f : 0.f;
        for (int j = 0; j < i; j++) acc -= Ld[i][j] * Wd[j][c];
        Wd[i][c] = acc / Ld[i][i];
    }
    float* Op = Out + (long)pair * sPairO + (long)I0 * ldo + I0;
    for (int i = 0; i < 64; i++) Op[(long)i * ldo + c] = Wd[i][c];
}

// off-diagonal blocks of triangular inverse: Linv_IJ = -Dinv_I * sum_{K=J..I-1} L_IK Linv_KJ
__global__ __launch_bounds__(256) void k_linvoff(const float* __restrict__ L, long sPair, int ld,
                                                 float* __restrict__ Linv, long sPairO, int ldo,
                                                 int d) {
    int pair = blockIdx.x, J = blockIdx.y, I = J + d;
    int I0 = I * 64, J0 = J * 64;
    int t = threadIdx.x, tx = t & 15, ty = t >> 4;
    __shared__ float La[64][66], Lb[64][66], Ss[64][66];
    float acc[4][4] = {};
    for (int K = J; K < I; K++) {
        int K0 = K * 64;
        for (int e = t; e < 4096; e += 256) {
            int i = e >> 6, k = e & 63;
            La[i][k] = L[(long)pair * sPair + (long)(I0 + i) * ld + K0 + k];
            Lb[i][k] = Linv[(long)pair * sPairO + (long)(K0 + i) * ldo + J0 + k];
        }
        __syncthreads();
#pragma unroll 4
        for (int kk = 0; kk < 64; kk++) {
            float a[4], b[4];
#pragma unroll
            for (int q = 0; q < 4; q++) { a[q] = La[ty + 16 * q][kk]; b[q] = Lb[kk][tx + 16 * q]; }
#pragma unroll
            for (int q = 0; q < 4; q++)
#pragma unroll
                for (int r = 0; r < 4; r++) acc[q][r] += a[q] * b[r];
        }
        __syncthreads();
    }
#pragma unroll
    for (int q = 0; q < 4; q++)
#pragma unroll
        for (int r = 0; r < 4; r++) Ss[ty + 16 * q][tx + 16 * r] = acc[q][r];
    for (int e = t; e < 4096; e += 256) {
        int i = e >> 6, k = e & 63;
        La[i][k] = Linv[(long)pair * sPairO + (long)(I0 + i) * ldo + I0 + k];
    }
    __syncthreads();
    float out[4][4] = {};
#pragma unroll 4
    for (int kk = 0; kk < 64; kk++) {
        float a[4], b[4];
#pragma unroll
        for (int q = 0; q < 4; q++) { a[q] = La[ty + 16 * q][kk]; b[q] = Ss[kk][tx + 16 * q]; }
#pragma unroll
        for (int q = 0; q < 4; q++)
#pragma unroll
            for (int r = 0; r < 4; r++) out[q][r] += a[q] * b[r];
    }
#pragma unroll
    for (int q = 0; q < 4; q++)
#pragma unroll
        for (int r = 0; r < 4; r++)
            Linv[(long)pair * sPairO + (long)(I0 + ty + 16 * q) * ldo + J0 + tx + 16 * r] = -out[q][r];
}

// a2 = Linv128 * m_old ; m_new = A1^T a2 + u_mean ; write m_joint
__global__ __launch_bounds__(128) void k_stage1vec(const float* __restrict__ Linv128,
                                                   const float* __restrict__ A1,
                                                   const float* __restrict__ m_old,
                                                   const float* __restrict__ u_mean,
                                                   float* __restrict__ MJ) {
    int pair = blockIdx.x, o = pair & 31, t = threadIdx.x;
    __shared__ float mo[128], a2[128];
    mo[t] = m_old[o * 128 + t];
    __syncthreads();
    const float* Lr = Linv128 + (long)pair * 16384 + (long)t * 128;
    float acc = 0.f;
    for (int j = 0; j <= t; j++) acc += Lr[j] * mo[j];
    a2[t] = acc;
    __syncthreads();
    float m = 0.f;
    for (int i = 0; i < 128; i++) m += A1[(long)pair * 16384 + (long)i * 128 + t] * a2[i];
    MJ[pair * 256 + t] = mo[t];
    MJ[pair * 256 + 128 + t] = m + u_mean[o * 128 + t];
}

// assemble COVj = cov_joint + JIT*I
__global__ __launch_bounds__(256) void k_assemble(const float* __restrict__ SOLD,
                                                  const float* __restrict__ SCUR,
                                                  const float* __restrict__ TRb,
                                                  const float* __restrict__ BRb,
                                                  float* __restrict__ COV) {
    int pair = blockIdx.x, quad = blockIdx.y, o = pair & 31, t = threadIdx.x;
    long base = (long)pair * M2 * M2;
    for (int e = t; e < 16384; e += 256) {
        int i = e >> 7, j = e & 127;
        if (quad == 0) {
            COV[base + (long)i * 256 + j] = SOLD[(long)o * 16384 + e] + ((i == j) ? JIT : 0.f);
        } else if (quad == 1) {
            COV[base + (long)i * 256 + 128 + j] = TRb[(long)pair * 16384 + e];
        } else if (quad == 2) {
            COV[base + (long)(128 + i) * 256 + j] = TRb[(long)pair * 16384 + (long)j * 128 + i];
        } else {
            COV[base + (long)(128 + i) * 256 + 128 + j] =
                SCUR[(long)o * 16384 + e] + BRb[(long)pair * 16384 + e] + ((i == j) ? JIT : 0.f);
        }
    }
}

// c = Linv^T (Linv * m_joint)
__global__ __launch_bounds__(256) void k_cvec(const float* __restrict__ Linv,
                                              const float* __restrict__ MJ,
                                              float* __restrict__ CV) {
    int pair = blockIdx.x, t = threadIdx.x;
    __shared__ float mj[256], tmp[256];
    mj[t] = MJ[pair * 256 + t];
    __syncthreads();
    const float* Lp = Linv + (long)pair * 65536;
    float acc = 0.f;
    for (int j = 0; j <= t; j++) acc += Lp[(long)t * 256 + j] * mj[j];
    tmp[t] = acc;
    __syncthreads();
    float c = 0.f;
    for (int k = t; k < 256; k++) c += Lp[(long)k * 256 + t] * tmp[k];
    CV[pair * 256 + t] = c;
}

// generic batched SGEMM: C = alpha * opA(A) * opB(B) (+C if accum==1; +Dm if accum==2)
// tiles3: blockIdx.y in {0,1,2} -> (I0,J0) in {(0,0),(128,128),(128,0)+mirror}
template <int TA, int TB>
__global__ __launch_bounds__(256) void k_bmm(const float* __restrict__ A, long aSH, long aSO, int lda,
                                             const float* __restrict__ B, long bSH, long bSO, int ldb,
                                             float* __restrict__ C, long cSH, long cSO, int ldc,
                                             const float* __restrict__ Dm,
                                             int Ksz, int kLoMode, int kHiMode, float alpha,
                                             int accum, int tiles3) {
    int pair = blockIdx.x;
    int h = pair >> 5, o = pair & 31;
    const float* Ap = A + (long)h * aSH + (long)o * aSO;
    const float* Bp = B + (long)h * bSH + (long)o * bSO;
    float* Cp = C + (long)h * cSH + (long)o * cSO;
    const float* Dp = Dm ? (Dm + (long)h * cSH + (long)o * cSO) : nullptr;
    int I0, J0, mir = 0;
    if (tiles3) {
        int qb = blockIdx.y;
        I0 = (qb == 0) ? 0 : 128;
        J0 = (qb == 2) ? 0 : I0;
        mir = (qb == 2);
    } else {
        I0 = blockIdx.y * 128;
        J0 = blockIdx.z * 128;
    }
    int k0 = (kLoMode == 0) ? 0 : (kLoMode == 1) ? I0 : (kLoMode == 2) ? J0 : max(I0, J0);
    int k1 = (kHiMode == 0) ? Ksz : (kHiMode == 1) ? min(Ksz, I0 + 128) : min(Ksz, min(I0, J0) + 128);
    int t = threadIdx.x, tx = t & 15, ty = t >> 4;
    __shared__ float As[16][132], Bs[16][132];
    float acc[8][8] = {};
    for (int kt = k0; kt < k1; kt += 16) {
#pragma unroll
        for (int q = 0; q < 8; q++) {
            int e = q * 256 + t;
            if (TA) {
                int kk = e >> 7, m = e & 127;
                As[kk][m] = Ap[(long)(kt + kk) * lda + I0 + m];
            } else {
                int m = e >> 4, kk = e & 15;
                As[kk][m] = Ap[(long)(I0 + m) * lda + kt + kk];
            }
            if (TB) {
                int n = e >> 4, kk = e & 15;
                Bs[kk][n] = Bp[(long)(J0 + n) * ldb + kt + kk];
            } else {
                int kk = e >> 7, n = e & 127;
                Bs[kk][n] = Bp[(long)(kt + kk) * ldb + J0 + n];
            }
        }
        __syncthreads();
#pragma unroll
        for (int kk = 0; kk < 16; kk++) {
            float a[8], b[8];
#pragma unroll
            for (int q = 0; q < 8; q++) { a[q] = As[kk][ty + 16 * q]; b[q] = Bs[kk][tx + 16 * q]; }
#pragma unroll
            for (int q = 0; q < 8; q++)
#pragma unroll
                for (int r = 0; r < 8; r++) acc[q][r] += a[q] * b[r];
        }
        __syncthreads();
    }
#pragma unroll
    for (int q = 0; q < 8; q++)
#pragma unroll
        for (int r = 0; r < 8; r++) {
            int row = I0 + ty + 16 * q, col = J0 + tx + 16 * r;
            long idx = (long)row * ldc + col;
            float v = alpha * acc[q][r];
            if (accum == 1) v += Cp[idx];
            if (accum == 2) v += Dp[idx];
            Cp[idx] = v;
            if (mir) Cp[(long)col * ldc + row] = v;
        }
}

// split fp32 G -> bf16 hi + bf16 lo planes
__global__ __launch_bounds__(256) void k_gsplit(const float* __restrict__ G,
                                                ushort_t* __restrict__ hi,
                                                ushort_t* __restrict__ lo) {
    long idx = ((long)blockIdx.x * 256 + threadIdx.x) * 4;
    float4 g = *(const float4*)(G + idx);
    v4us h, l;
    float gv[4] = {g.x, g.y, g.z, g.w};
#pragma unroll
    for (int e = 0; e < 4; e++) {
        unsigned int u = __float_as_uint(gv[e]);
        unsigned short hb = (unsigned short)(u >> 16);
        float hf = __uint_as_float((unsigned int)hb << 16);
        float r = gv[e] - hf;
        unsigned short lb = (unsigned short)(__float_as_uint(r) >> 16);
        h[e] = hb;
        l[e] = lb;
    }
    *(v4us*)(hi + idx) = h;
    *(v4us*)(lo + idx) = l;
}

// fused final kernel (MFMA): per (pair, 64-col b-tile):
// build K tile bf16 in LDS (transposed), Y = (Ghi+Glo) @ K via mfma 32x32x16,
// q[b] = diag(K^T Y), mu[b] = K^T c (fp32 during build), var = sf2 - q
#define KTP 280  // padded row length (bf16 elems) of KbT; 560B = 16B-aligned
__global__ __launch_bounds__(256) void k_kb3(const float* __restrict__ ZS, const float* __restrict__ ZN,
                                             const float* __restrict__ XS, const float* __restrict__ XN,
                                             const float* __restrict__ SF2,
                                             const ushort_t* __restrict__ Ghi,
                                             const ushort_t* __restrict__ Glo,
                                             const float* __restrict__ CV, float* __restrict__ out) {
    int bt = blockIdx.x;    // 16 tiles of 64 b-cols
    int pair = blockIdx.y;  // 128
    int h = pair >> 5;
    int t = threadIdx.x;
    int w = t >> 6;         // wave id 0..3
    int lane = t & 63;
    int l31 = lane & 31, lhalf = lane >> 5;

    __shared__ __align__(16) ushort_t KbT[64][KTP];  // [b][j] bf16
    __shared__ float qpart[4][64];
    __shared__ float mup[4][64];

    float sf2 = SF2[h];

    // ---- build phase: thread (w, b=t&63) computes K(z_j, x_b) for j in [w*64, w*64+64)
    {
        int b = t & 63;
        long bg = (long)h * B_ + bt * 64 + b;
        const float4* xrow = (const float4*)(XS + bg * 16);
        float4 x0 = xrow[0], x1 = xrow[1], x2 = xrow[2], x3 = xrow[3];
        float xn = XN[bg];
        float mupart = 0.f;
        const float* cvp = CV + pair * 256;
        const float* znp = ZN + pair * 256;
#pragma unroll 2
        for (int j8 = 0; j8 < 8; j8++) {
            v8us kb8;
#pragma unroll
            for (int e = 0; e < 8; e++) {
                int j = w * 64 + j8 * 8 + e;
                const float4* zrow = (const float4*)(ZS + ((long)pair * 256 + j) * 16);
                float4 z0 = zrow[0], z1 = zrow[1], z2 = zrow[2], z3 = zrow[3];
                float dot = z0.x * x0.x + z0.y * x0.y + z0.z * x0.z + z0.w * x0.w +
                            z1.x * x1.x + z1.y * x1.y + z1.z * x1.z + z1.w * x1.w +
                            z2.x * x2.x + z2.y * x2.y + z2.z * x2.z + z2.w * x2.w +
                            z3.x * x3.x + z3.y * x3.y + z3.z * x3.z + z3.w * x3.w;
                float d2 = fmaxf(znp[j] + xn - 2.f * dot, 0.f);
                float kv = sf2 * __expf(-0.5f * d2);
                mupart += cvp[j] * kv;
                unsigned int u = __float_as_uint(kv);
                u += 0x7fffu + ((u >> 16) & 1u);  // RNE to bf16
                kb8[e] = (unsigned short)(u >> 16);
            }
            *(v8us*)&KbT[b][w * 64 + j8 * 8] = kb8;
        }
        mup[w][b] = mupart;
    }
    __syncthreads();

    // ---- MFMA phase: Y[i=256][b=64]; wave w owns i in [w*64, w*64+64)
    v16f acc[2][2];
#pragma unroll
    for (int mt = 0; mt < 2; mt++)
#pragma unroll
        for (int nt = 0; nt < 2; nt++)
#pragma unroll
            for (int r = 0; r < 16; r++) acc[mt][nt][r] = 0.f;

    const ushort_t* GhiP = Ghi + (long)pair * 65536;
    const ushort_t* GloP = Glo + (long)pair * 65536;
    for (int k0 = 0; k0 < 256; k0 += 16) {
        v8bf bfr[2];
#pragma unroll
        for (int nt = 0; nt < 2; nt++)
            bfr[nt] = *(const v8bf*)&KbT[nt * 32 + l31][k0 + lhalf * 8];
#pragma unroll
        for (int mt = 0; mt < 2; mt++) {
            int i = w * 64 + mt * 32 + l31;
            v8bf ah = *(const v8bf*)(GhiP + (long)i * 256 + k0 + lhalf * 8);
            v8bf al = *(const v8bf*)(GloP + (long)i * 256 + k0 + lhalf * 8);
#pragma unroll
            for (int nt = 0; nt < 2; nt++) {
                acc[mt][nt] = __builtin_amdgcn_mfma_f32_32x32x16_bf16(ah, bfr[nt], acc[mt][nt], 0, 0, 0);
                acc[mt][nt] = __builtin_amdgcn_mfma_f32_32x32x16_bf16(al, bfr[nt], acc[mt][nt], 0, 0, 0);
            }
        }
    }

    // ---- reduction: q_b += K_ib * Y_ib over this wave's i-range
    float qp[2] = {0.f, 0.f};
#pragma unroll
    for (int mt = 0; mt < 2; mt++) {
#pragma unroll
        for (int nt = 0; nt < 2; nt++) {
            int b = nt * 32 + l31;
#pragma unroll
            for (int g = 0; g < 4; g++) {
                int ibase = w * 64 + mt * 32 + 8 * g + 4 * lhalf;
                v4us k4 = *(const v4us*)&KbT[b][ibase];
#pragma unroll
                for (int e = 0; e < 4; e++) {
                    float kv = __uint_as_float((unsigned int)k4[e] << 16);
                    qp[nt] += kv * acc[mt][nt][4 * g + e];
                }
            }
        }
    }
#pragma unroll
    for (int nt = 0; nt < 2; nt++) {
        qp[nt] += __shfl_down(qp[nt], 32, 64);
        if (lhalf == 0) qpart[w][nt * 32 + l31] = qp[nt];
    }
    __syncthreads();

    if (t < 64) {
        float mu = mup[0][t] + mup[1][t] + mup[2][t] + mup[3][t];
        float q = qpart[0][t] + qpart[1][t] + qpart[2][t] + qpart[3][t];
        long ob = (long)pair * 1024 + bt * 64 + t;
        out[ob] = mu;
        out[(long)H_ * O_ * B_ + ob] = sf2 - q;
    }
}

// ---------------------------------------------------------------------------
extern "C" void kernel_launch(void* const* d_in, const int* in_sizes, int n_in,
                              void* d_out, int out_size, void* d_ws, size_t ws_size,
                              hipStream_t stream) {
    const float* x = (const float*)d_in[0];
    const float* z = (const float*)d_in[1];
    const float* u_mean = (const float*)d_in[2];
    const float* u_tril_vec = (const float*)d_in[3];
    const float* m_old = (const float*)d_in[4];
    const float* L_old = (const float*)d_in[5];
    const float* z_old = (const float*)d_in[6];
    const float* theta = (const float*)d_in[7];

    const long BIGSZ = (long)HO * M2 * M2;  // 8388608
    const long MSZ = (long)HO * M_ * M_;    // 2097152
    const long OSZ = (long)O_ * M_ * M_;    // 524288
    const long SH2 = (long)O_ * M2 * M2;    // per-h stride of big arrays
    const long SO2 = (long)M2 * M2;
    const long SH1 = (long)O_ * M_ * M_;
    const long SO1 = (long)M_ * M_;

    float* ws = (float*)d_ws;
    long off = 0;
    float* BIG0 = ws + off; off += BIGSZ;  // KUU2 -> AINV
    float* BIG1 = ws + off; off += BIGSZ;  // UT -> COVj -> G
    float* BIG2 = ws + off; off += BIGSZ;  // Linv128|A1|A3|ATX (then TRb,BRb) -> LINV
    float* BIG3 = ws + off; off += BIGSZ;  // L256 -> P -> Ghi/Glo(bf16)
    float* SOLD = ws + off; off += OSZ;
    float* SCUR = ws + off; off += OSZ;
    float* ZS = ws + off; off += (long)HO * M2 * D_;
    float* XS = ws + off; off += (long)H_ * B_ * D_;
    float* ZN = ws + off; off += (long)HO * M2;
    float* XN = ws + off; off += (long)H_ * B_;
    float* MJ = ws + off; off += (long)HO * M2;
    float* CV = ws + off; off += (long)HO * M2;
    float* LSI = ws + off; off += H_ * D_;
    float* SF2v = ws + off; off += H_;

    float* UT = BIG1;
    float* KUU2 = BIG0;
    float* COV = BIG1;
    float* Linv128 = BIG2;            // slot 0
    float* A1 = BIG2 + MSZ;           // slot 1
    float* A3 = BIG2 + 2 * MSZ;       // slot 2
    float* ATX = BIG2 + 3 * MSZ;      // slot 3
    float* TRb = BIG2 + 2 * MSZ;      // reuse slot 2 (A3 dead)
    float* BRb = BIG2;                // reuse slot 0 (Linv128 dead)
    float* L256 = BIG3;
    float* LINV = BIG2;
    float* AINV = BIG0;
    float* Pb = BIG3;
    float* Gb = BIG1;
    ushort_t* Ghi = (ushort_t*)BIG3;  // P dead after G computed
    ushort_t* Glo = Ghi + BIGSZ;
    const long BRoff = 128L * M2 + 128;  // BR quadrant offset in a 256x256

    k_prep<<<1, 64, 0, stream>>>(theta, LSI, SF2v);
    k_scale_x<<<(H_ * B_ + 255) / 256, 256, 0, stream>>>(x, LSI, XS, XN);
    k_scale_z<<<HO * M2 / 256, 256, 0, stream>>>(z, z_old, LSI, ZS, ZN);
    k_unpack<<<(int)(OSZ / 256), 256, 0, stream>>>(u_tril_vec, UT);

    // S_old = L_old L_old^T ; S_cur = UT UT^T   (batched over o)
    k_bmm<0, 1><<<dim3(O_, 1, 1), 256, 0, stream>>>(L_old, 0, SO1, M_, L_old, 0, SO1, M_,
                                                    SOLD, 0, SO1, M_, nullptr, M_, 0, 0, 1.f, 0, 0);
    k_bmm<0, 1><<<dim3(O_, 1, 1), 256, 0, stream>>>(UT, 0, SO1, M_, UT, 0, SO1, M_,
                                                    SCUR, 0, SO1, M_, nullptr, M_, 0, 0, 1.f, 0, 0);

    k_kuu2<<<HO, 256, 0, stream>>>(ZS, ZN, SF2v, KUU2);
    // chol of TL 128x128 -> L256 TL
    k_chol128<<<HO, 128, 0, stream>>>(KUU2, SO2, M2, L256, SO2, M2);

    hipMemsetAsync(Linv128, 0, MSZ * sizeof(float), stream);
    k_diaginv<<<dim3(HO, 2), 64, 0, stream>>>(L256, SO2, M2, Linv128, SO1, M_);
    k_linvoff<<<dim3(HO, 1), 256, 0, stream>>>(L256, SO2, M2, Linv128, SO1, M_, 1);

    // A1 = Linv128 @ kuf (kuf = KUU2 rows 0..127, cols 128..255)
    k_bmm<0, 0><<<dim3(HO, 1, 1), 256, 0, stream>>>(Linv128, SH1, SO1, M_,
                                                    KUU2 + 128, SH2, SO2, M2,
                                                    A1, SH1, SO1, M_, nullptr, M_, 0, 0, 1.f, 0, 0);
    // A3 = Linv128 @ L_old
    k_bmm<0, 0><<<dim3(HO, 1, 1), 256, 0, stream>>>(Linv128, SH1, SO1, M_, L_old, 0, SO1, M_,
                                                    A3, SH1, SO1, M_, nullptr, M_, 0, 0, 1.f, 0, 0);
    k_stage1vec<<<HO, 128, 0, stream>>>(Linv128, A1, m_old, u_mean, MJ);

    // ATX = A3^T @ A1
    k_bmm<1, 0><<<dim3(HO, 1, 1), 256, 0, stream>>>(A3, SH1, SO1, M_, A1, SH1, SO1, M_,
                                                    ATX, SH1, SO1, M_, nullptr, M_, 0, 0, 1.f, 0, 0);
    // TRb = L_old @ ATX   (overwrites A3 slot — A3 dead)
    k_bmm<0, 0><<<dim3(HO, 1, 1), 256, 0, stream>>>(L_old, 0, SO1, M_, ATX, SH1, SO1, M_,
                                                    TRb, SH1, SO1, M_, nullptr, M_, 0, 0, 1.f, 0, 0);
    // BRb = ATX^T @ ATX   (overwrites Linv128 slot — dead after stage1vec/A1/A3)
    k_bmm<1, 0><<<dim3(HO, 1, 1), 256, 0, stream>>>(ATX, SH1, SO1, M_, ATX, SH1, SO1, M_,
                                                    BRb, SH1, SO1, M_, nullptr, M_, 0, 0, 1.f, 0, 0);

    k_assemble<<<dim3(HO, 4), 256, 0, stream>>>(SOLD, SCUR, TRb, BRb, COV);

    // L256 BL = A1^T
    k_copyT<<<HO, 256, 0, stream>>>(A1, L256);
    // Schur: KUU2_BR -= A1^T A1
    k_bmm<1, 0><<<dim3(HO, 1, 1), 256, 0, stream>>>(A1, SH1, SO1, M_, A1, SH1, SO1, M_,
                                                    KUU2 + BRoff, SH2, SO2, M2, nullptr,
                                                    M_, 0, 0, -1.f, 1, 0);
    // L22 = chol(S22) -> L256 BR
    k_chol128<<<HO, 128, 0, stream>>>(KUU2 + BRoff, SO2, M2, L256 + BRoff, SO2, M2);

    // LINV = L256^{-1}  (overwrites all of BIG2; A1/TRb/BRb consumed above)
    hipMemsetAsync(LINV, 0, BIGSZ * sizeof(float), stream);
    k_diaginv<<<dim3(HO, 4), 64, 0, stream>>>(L256, SO2, M2, LINV, SO2, M2);
    k_linvoff<<<dim3(HO, 3), 256, 0, stream>>>(L256, SO2, M2, LINV, SO2, M2, 1);
    k_linvoff<<<dim3(HO, 2), 256, 0, stream>>>(L256, SO2, M2, LINV, SO2, M2, 2);
    k_linvoff<<<dim3(HO, 1), 256, 0, stream>>>(L256, SO2, M2, LINV, SO2, M2, 3);

    k_cvec<<<HO, 256, 0, stream>>>(LINV, MJ, CV);

    // AINV = LINV^T @ LINV  (symmetric: 3 tiles + mirror; k >= max(I0,J0))
    k_bmm<1, 0><<<dim3(HO, 3, 1), 256, 0, stream>>>(LINV, SH2, SO2, M2, LINV, SH2, SO2, M2,
                                                    AINV, SH2, SO2, M2, nullptr,
                                                    M2, 3, 0, 1.f, 0, 1);
    // P = COVj @ AINV  (L256 dead -> BIG3)
    k_bmm<0, 0><<<dim3(HO, 2, 2), 256, 0, stream>>>(COV, SH2, SO2, M2, AINV, SH2, SO2, M2,
                                                    Pb, SH2, SO2, M2, nullptr,
                                                    M2, 0, 0, 1.f, 0, 0);
    // G = AINV - P^T @ AINV  (symmetric: 3 tiles + mirror; COVj dead -> BIG1)
    k_bmm<1, 0><<<dim3(HO, 3, 1), 256, 0, stream>>>(Pb, SH2, SO2, M2, AINV, SH2, SO2, M2,
                                                    Gb, SH2, SO2, M2, AINV,
                                                    M2, 0, 0, -1.f, 2, 1);

    // split G into bf16 hi/lo planes (P dead -> BIG3)
    k_gsplit<<<(int)(BIGSZ / 1024), 256, 0, stream>>>(Gb, Ghi, Glo);

    k_kb3<<<dim3(16, HO), 256, 0, stream>>>(ZS, ZN, XS, XN, SF2v, Ghi, Glo, CV, (float*)d_out);
}

// Round 4
// 1080.840 us; speedup vs baseline: 2.8400x; 1.5970x over previous
//
#include <hip/hip_runtime.h>

#define H_ 4
#define O_ 32
#define HO 128
#define M_ 128
#define M2 256
#define D_ 16
#define B_ 1024
#define JIT 1e-4f

typedef unsigned short ushort_t;
typedef __bf16 v8bf __attribute__((ext_vector_type(8)));
typedef float v16f __attribute__((ext_vector_type(16)));
typedef unsigned short v8us __attribute__((ext_vector_type(8)));
typedef unsigned short v4us __attribute__((ext_vector_type(4)));

// ---------------------------------------------------------------------------
// prep: inverse lengthscales and sf2
__global__ void k_prep(const float* __restrict__ theta, float* __restrict__ LSI,
                       float* __restrict__ SF2) {
    int t = threadIdx.x;  // 64 threads
    if (t < H_ * D_) {
        int h = t / D_, d = t % D_;
        LSI[h * D_ + d] = __expf(-theta[h * (D_ + 1) + 1 + d]);
    }
    if (t < H_) SF2[t] = __expf(theta[t * (D_ + 1)]);
}

// scaled x rows + squared norms
__global__ void k_scale_x(const float* __restrict__ x, const float* __restrict__ LSI,
                          float* __restrict__ XS, float* __restrict__ XN) {
    int idx = blockIdx.x * 256 + threadIdx.x;  // h*B + b
    if (idx >= H_ * B_) return;
    int h = idx / B_, b = idx % B_;
    float s = 0.f;
#pragma unroll
    for (int d = 0; d < D_; d++) {
        float v = x[b * D_ + d] * LSI[h * D_ + d];
        XS[(long)idx * D_ + d] = v;
        s += v * v;
    }
    XN[idx] = s;
}

// scaled z_joint rows + squared norms ([z_old; z] per o, per h)
__global__ void k_scale_z(const float* __restrict__ z, const float* __restrict__ z_old,
                          const float* __restrict__ LSI, float* __restrict__ ZS,
                          float* __restrict__ ZN) {
    int idx = blockIdx.x * 256 + threadIdx.x;  // (h*O+o)*256 + i
    int i = idx & 255;
    int pair = idx >> 8;
    int h = pair >> 5, o = pair & 31;
    const float* src = (i < M_) ? (z_old + ((long)o * M_ + i) * D_)
                                : (z + ((long)o * M_ + (i - M_)) * D_);
    float s = 0.f;
#pragma unroll
    for (int d = 0; d < D_; d++) {
        float v = src[d] * LSI[h * D_ + d];
        ZS[(long)idx * D_ + d] = v;
        s += v * v;
    }
    ZN[idx] = s;
}

// unpack packed tril vec -> dense lower [O][128][128]
__global__ void k_unpack(const float* __restrict__ vec, float* __restrict__ UT) {
    long idx = (long)blockIdx.x * 256 + threadIdx.x;
    int o = (int)(idx >> 14);
    int e = (int)(idx & 16383);
    int i = e >> 7, j = e & 127;
    float v = (j <= i) ? vec[(long)o * (M_ * (M_ + 1) / 2) + i * (i + 1) / 2 + j] : 0.f;
    UT[idx] = v;
}

// kuu2 = k_rbf(z_joint, z_joint) + JIT*I   [HO][256][256]
__global__ __launch_bounds__(256) void k_kuu2(const float* __restrict__ ZS,
                                              const float* __restrict__ ZN,
                                              const float* __restrict__ SF2,
                                              float* __restrict__ K2) {
    int pair = blockIdx.x;
    int h = pair >> 5;
    int t = threadIdx.x;
    __shared__ float zs[M2][D_];
    __shared__ float zn[M2];
    for (int e = t; e < M2 * D_; e += 256) zs[e / D_][e % D_] = ZS[(long)pair * M2 * D_ + e];
    zn[t] = ZN[pair * M2 + t];
    __syncthreads();
    float sf2 = SF2[h];
    float my[D_];
#pragma unroll
    for (int d = 0; d < D_; d++) my[d] = zs[t][d];
    float myn = zn[t];
    for (int q = 0; q < M2; q++) {
        float dot = 0.f;
#pragma unroll
        for (int d = 0; d < D_; d++) dot += zs[q][d] * my[d];
        float d2 = fmaxf(zn[q] + myn - 2.f * dot, 0.f);
        float v = sf2 * __expf(-0.5f * d2);
        if (q == t) v += JIT;
        K2[(long)pair * M2 * M2 + (long)q * M2 + t] = v;
    }
}

// blocked (BK=32) in-LDS Cholesky of a 128x128 block, 256 threads.
// Packed lower storage; unscaled GE sweeps on diag block (1 barrier/step),
// deferred column scaling, register trsm, 4x4-register-tiled syrk.
__global__ __launch_bounds__(256) void k_chol128(const float* __restrict__ src, long sps, int ldsrc,
                                                 float* __restrict__ dst, long spd, int lddst) {
    int pair = blockIdx.x, t = threadIdx.x;
    __shared__ float Ap[M_ * (M_ + 1) / 2];  // 8256 floats, packed lower
    __shared__ float rsq[32];
    const float* S = src + (long)pair * sps;
    for (int e = t; e < M_ * (M_ + 1) / 2; e += 256) {
        int i = (int)((sqrtf(8.f * e + 1.f) - 1.f) * 0.5f);
        while ((i + 1) * (i + 2) / 2 <= e) i++;
        while (i * (i + 1) / 2 > e) i--;
        int j = e - i * (i + 1) / 2;
        Ap[e] = S[(long)i * ldsrc + j];
    }
    // per-thread static (i,j) pairs covering the 32x32 lower triangle (528 elems)
    int pi[3], pj[3];
#pragma unroll
    for (int u = 0; u < 3; u++) {
        int p = t + u * 256;
        if (p < 528) {
            int i = (int)((sqrtf(8.f * p + 1.f) - 1.f) * 0.5f);
            while ((i + 1) * (i + 2) / 2 <= p) i++;
            while (i * (i + 1) / 2 > p) i--;
            pi[u] = i;
            pj[u] = p - i * (i + 1) / 2;
        } else {
            pi[u] = -1;
            pj[u] = 0;
        }
    }
    __syncthreads();

    for (int kb = 0; kb < 4; kb++) {
        int c0 = kb * 32;
        // --- A: unscaled rank-1 sweeps on the diag block
        for (int k = 0; k < 32; k++) {
            int kc = c0 + k;
            float rd = 1.f / Ap[kc * (kc + 1) / 2 + kc];
#pragma unroll
            for (int u = 0; u < 3; u++) {
                int i = pi[u], j = pj[u];
                if (i > k && j > k) {
                    int gi = c0 + i, gj = c0 + j;
                    Ap[gi * (gi + 1) / 2 + gj] -=
                        Ap[gi * (gi + 1) / 2 + kc] * Ap[gj * (gj + 1) / 2 + kc] * rd;
                }
            }
            __syncthreads();
        }
        // --- scale pass: L[:,j] = A[:,j] * rsqrt(d_j)  (diag becomes sqrt(d))
        if (t < 32) {
            int g = c0 + t;
            rsq[t] = rsqrtf(Ap[g * (g + 1) / 2 + g]);
        }
        __syncthreads();
#pragma unroll
        for (int u = 0; u < 3; u++) {
            int i = pi[u], j = pj[u];
            if (i >= 0) {
                int gi = c0 + i, gj = c0 + j;
                Ap[gi * (gi + 1) / 2 + gj] *= rsq[j];
            }
        }
        __syncthreads();

        int R = M_ - c0 - 32;
        if (R > 0) {
            // --- B: trsm: panel rows solve against L11 (row per thread, regs)
            if (t < R) {
                int gi = c0 + 32 + t;
                int base = gi * (gi + 1) / 2 + c0;
                float xr[32];
#pragma unroll
                for (int j = 0; j < 32; j++) xr[j] = Ap[base + j];
#pragma unroll
                for (int q = 0; q < 32; q++) {
                    float xq = xr[q] * rsq[q];
                    xr[q] = xq;
#pragma unroll
                    for (int j = q + 1; j < 32; j++)
                        xr[j] -= xq * Ap[(c0 + j) * (c0 + j + 1) / 2 + c0 + q];
                }
#pragma unroll
                for (int j = 0; j < 32; j++) Ap[base + j] = xr[j];
            }
            __syncthreads();
            // --- C: syrk trailing update, 4x4 register tiles over lower triangle
            int nb = R >> 2;
            int ntile = nb * (nb + 1) / 2;
            for (int tp = t; tp < ntile; tp += 256) {
                int bi = (int)((sqrtf(8.f * tp + 1.f) - 1.f) * 0.5f);
                while ((bi + 1) * (bi + 2) / 2 <= tp) bi++;
                while (bi * (bi + 1) / 2 > tp) bi--;
                int bj = tp - bi * (bi + 1) / 2;
                int i0 = c0 + 32 + bi * 4, j0 = c0 + 32 + bj * 4;
                float acc[4][4] = {};
                for (int k = 0; k < 32; k++) {
                    float a[4], b[4];
#pragma unroll
                    for (int q = 0; q < 4; q++) a[q] = Ap[(i0 + q) * (i0 + q + 1) / 2 + c0 + k];
#pragma unroll
                    for (int r = 0; r < 4; r++) b[r] = Ap[(j0 + r) * (j0 + r + 1) / 2 + c0 + k];
#pragma unroll
                    for (int q = 0; q < 4; q++)
#pragma unroll
                        for (int r = 0; r < 4; r++) acc[q][r] += a[q] * b[r];
                }
#pragma unroll
                for (int q = 0; q < 4; q++)
#pragma unroll
                    for (int r = 0; r < 4; r++) {
                        int gi = i0 + q, gj = j0 + r;
                        if (gj <= gi) Ap[gi * (gi + 1) / 2 + gj] -= acc[q][r];
                    }
            }
            __syncthreads();
        }
    }

    float* Dst = dst + (long)pair * spd;
    for (int e = t; e < M_ * M_; e += 256) {
        int i = e >> 7, j = e & 127;
        Dst[(long)i * lddst + j] = (j <= i) ? Ap[i * (i + 1) / 2 + j] : 0.f;
    }
}

// transpose A1 [pair][128][128] into BL quadrant of L256 [pair][256][256]
__global__ __launch_bounds__(256) void k_copyT(const float* __restrict__ A1, float* __restrict__ L) {
    int pair = blockIdx.x, t = threadIdx.x;
    int tx = t & 31, ty = t >> 5;  // 8 rows of 32
    __shared__ float tl[32][33];
    for (int bi = 0; bi < 4; bi++)
        for (int bj = 0; bj < 4; bj++) {
            for (int r = ty; r < 32; r += 8)
                tl[r][tx] = A1[(long)pair * 16384 + (long)(bj * 32 + r) * 128 + bi * 32 + tx];
            __syncthreads();
            for (int r = ty; r < 32; r += 8)
                L[(long)pair * 65536 + (long)(128 + bi * 32 + r) * 256 + bj * 32 + tx] = tl[tx][r];
            __syncthreads();
        }
}

// invert 64x64 lower-tri diagonal blocks: grid (nPair, NB), 64 threads
__global__ __launch_bounds__(64) void k_diaginv(const float* __restrict__ L, long sPair, int ld,
                                                float* __restrict__ Out, long sPairO, int ldo) {
    int pair = blockIdx.x, I0 = blockIdx.y * 64;
    int c = threadIdx.x;
    __shared__ float Ld[64][66];
    __shared__ float Wd[64][66];
    const float* Lp = L + (long)pair * sPair + (long)I0 * ld + I0;
    for (int e = c; e < 4096; e += 64) {
        int i = e >> 6, j = e & 63;
        Ld[i][j] = Lp[(long)i * ld + j];
    }
    __syncthreads();
    for (int i = 0; i < 64; i++) {
        float acc = (i == c) ? 1.f : 0.f;
        for (int j = 0; j < i; j++) acc -= Ld[i][j] * Wd[j][c];
        Wd[i][c] = acc / Ld[i][i];
    }
    float* Op = Out + (long)pair * sPairO + (long)I0 * ldo + I0;
    for (int i = 0; i < 64; i++) Op[(long)i * ldo + c] = Wd[i][c];
}

// off-diagonal blocks of triangular inverse: Linv_IJ = -Dinv_I * sum_{K=J..I-1} L_IK Linv_KJ
__global__ __launch_bounds__(256) void k_linvoff(const float* __restrict__ L, long sPair, int ld,
                                                 float* __restrict__ Linv, long sPairO, int ldo,
                                                 int d) {
    int pair = blockIdx.x, J = blockIdx.y, I = J + d;
    int I0 = I * 64, J0 = J * 64;
    int t = threadIdx.x, tx = t & 15, ty = t >> 4;
    __shared__ float La[64][66], Lb[64][66], Ss[64][66];
    float acc[4][4] = {};
    for (int K = J; K < I; K++) {
        int K0 = K * 64;
        for (int e = t; e < 4096; e += 256) {
            int i = e >> 6, k = e & 63;
            La[i][k] = L[(long)pair * sPair + (long)(I0 + i) * ld + K0 + k];
            Lb[i][k] = Linv[(long)pair * sPairO + (long)(K0 + i) * ldo + J0 + k];
        }
        __syncthreads();
#pragma unroll 4
        for (int kk = 0; kk < 64; kk++) {
            float a[4], b[4];
#pragma unroll
            for (int q = 0; q < 4; q++) { a[q] = La[ty + 16 * q][kk]; b[q] = Lb[kk][tx + 16 * q]; }
#pragma unroll
            for (int q = 0; q < 4; q++)
#pragma unroll
                for (int r = 0; r < 4; r++) acc[q][r] += a[q] * b[r];
        }
        __syncthreads();
    }
#pragma unroll
    for (int q = 0; q < 4; q++)
#pragma unroll
        for (int r = 0; r < 4; r++) Ss[ty + 16 * q][tx + 16 * r] = acc[q][r];
    for (int e = t; e < 4096; e += 256) {
        int i = e >> 6, k = e & 63;
        La[i][k] = Linv[(long)pair * sPairO + (long)(I0 + i) * ldo + I0 + k];
    }
    __syncthreads();
    float out[4][4] = {};
#pragma unroll 4
    for (int kk = 0; kk < 64; kk++) {
        float a[4], b[4];
#pragma unroll
        for (int q = 0; q < 4; q++) { a[q] = La[ty + 16 * q][kk]; b[q] = Ss[kk][tx + 16 * q]; }
#pragma unroll
        for (int q = 0; q < 4; q++)
#pragma unroll
            for (int r = 0; r < 4; r++) out[q][r] += a[q] * b[r];
    }
#pragma unroll
    for (int q = 0; q < 4; q++)
#pragma unroll
        for (int r = 0; r < 4; r++)
            Linv[(long)pair * sPairO + (long)(I0 + ty + 16 * q) * ldo + J0 + tx + 16 * r] = -out[q][r];
}

// a2 = Linv128 * m_old ; m_new = A1^T a2 + u_mean ; write m_joint
__global__ __launch_bounds__(128) void k_stage1vec(const float* __restrict__ Linv128,
                                                   const float* __restrict__ A1,
                                                   const float* __restrict__ m_old,
                                                   const float* __restrict__ u_mean,
                                                   float* __restrict__ MJ) {
    int pair = blockIdx.x, o = pair & 31, t = threadIdx.x;
    __shared__ float mo[128], a2[128];
    mo[t] = m_old[o * 128 + t];
    __syncthreads();
    const float* Lr = Linv128 + (long)pair * 16384 + (long)t * 128;
    float acc = 0.f;
    for (int j = 0; j <= t; j++) acc += Lr[j] * mo[j];
    a2[t] = acc;
    __syncthreads();
    float m = 0.f;
    for (int i = 0; i < 128; i++) m += A1[(long)pair * 16384 + (long)i * 128 + t] * a2[i];
    MJ[pair * 256 + t] = mo[t];
    MJ[pair * 256 + 128 + t] = m + u_mean[o * 128 + t];
}

// assemble COVj = cov_joint + JIT*I
__global__ __launch_bounds__(256) void k_assemble(const float* __restrict__ SOLD,
                                                  const float* __restrict__ SCUR,
                                                  const float* __restrict__ TRb,
                                                  const float* __restrict__ BRb,
                                                  float* __restrict__ COV) {
    int pair = blockIdx.x, quad = blockIdx.y, o = pair & 31, t = threadIdx.x;
    long base = (long)pair * M2 * M2;
    for (int e = t; e < 16384; e += 256) {
        int i = e >> 7, j = e & 127;
        if (quad == 0) {
            COV[base + (long)i * 256 + j] = SOLD[(long)o * 16384 + e] + ((i == j) ? JIT : 0.f);
        } else if (quad == 1) {
            COV[base + (long)i * 256 + 128 + j] = TRb[(long)pair * 16384 + e];
        } else if (quad == 2) {
            COV[base + (long)(128 + i) * 256 + j] = TRb[(long)pair * 16384 + (long)j * 128 + i];
        } else {
            COV[base + (long)(128 + i) * 256 + 128 + j] =
                SCUR[(long)o * 16384 + e] + BRb[(long)pair * 16384 + e] + ((i == j) ? JIT : 0.f);
        }
    }
}

// c = Linv^T (Linv * m_joint)
__global__ __launch_bounds__(256) void k_cvec(const float* __restrict__ Linv,
                                              const float* __restrict__ MJ,
                                              float* __restrict__ CV) {
    int pair = blockIdx.x, t = threadIdx.x;
    __shared__ float mj[256], tmp[256];
    mj[t] = MJ[pair * 256 + t];
    __syncthreads();
    const float* Lp = Linv + (long)pair * 65536;
    float acc = 0.f;
    for (int j = 0; j <= t; j++) acc += Lp[(long)t * 256 + j] * mj[j];
    tmp[t] = acc;
    __syncthreads();
    float c = 0.f;
    for (int k = t; k < 256; k++) c += Lp[(long)k * 256 + t] * tmp[k];
    CV[pair * 256 + t] = c;
}

// generic batched SGEMM: C = alpha * opA(A) * opB(B) (+C if accum==1; +Dm if accum==2)
// tiles3: blockIdx.y in {0,1,2} -> (I0,J0) in {(0,0),(128,128),(128,0)+mirror}
template <int TA, int TB>
__global__ __launch_bounds__(256) void k_bmm(const float* __restrict__ A, long aSH, long aSO, int lda,
                                             const float* __restrict__ B, long bSH, long bSO, int ldb,
                                             float* __restrict__ C, long cSH, long cSO, int ldc,
                                             const float* __restrict__ Dm,
                                             int Ksz, int kLoMode, int kHiMode, float alpha,
                                             int accum, int tiles3) {
    int pair = blockIdx.x;
    int h = pair >> 5, o = pair & 31;
    const float* Ap = A + (long)h * aSH + (long)o * aSO;
    const float* Bp = B + (long)h * bSH + (long)o * bSO;
    float* Cp = C + (long)h * cSH + (long)o * cSO;
    const float* Dp = Dm ? (Dm + (long)h * cSH + (long)o * cSO) : nullptr;
    int I0, J0, mir = 0;
    if (tiles3) {
        int qb = blockIdx.y;
        I0 = (qb == 0) ? 0 : 128;
        J0 = (qb == 2) ? 0 : I0;
        mir = (qb == 2);
    } else {
        I0 = blockIdx.y * 128;
        J0 = blockIdx.z * 128;
    }
    int k0 = (kLoMode == 0) ? 0 : (kLoMode == 1) ? I0 : (kLoMode == 2) ? J0 : max(I0, J0);
    int k1 = (kHiMode == 0) ? Ksz : (kHiMode == 1) ? min(Ksz, I0 + 128) : min(Ksz, min(I0, J0) + 128);
    int t = threadIdx.x, tx = t & 15, ty = t >> 4;
    __shared__ float As[16][132], Bs[16][132];
    float acc[8][8] = {};
    for (int kt = k0; kt < k1; kt += 16) {
#pragma unroll
        for (int q = 0; q < 8; q++) {
            int e = q * 256 + t;
            if (TA) {
                int kk = e >> 7, m = e & 127;
                As[kk][m] = Ap[(long)(kt + kk) * lda + I0 + m];
            } else {
                int m = e >> 4, kk = e & 15;
                As[kk][m] = Ap[(long)(I0 + m) * lda + kt + kk];
            }
            if (TB) {
                int n = e >> 4, kk = e & 15;
                Bs[kk][n] = Bp[(long)(J0 + n) * ldb + kt + kk];
            } else {
                int kk = e >> 7, n = e & 127;
                Bs[kk][n] = Bp[(long)(kt + kk) * ldb + J0 + n];
            }
        }
        __syncthreads();
#pragma unroll
        for (int kk = 0; kk < 16; kk++) {
            float a[8], b[8];
#pragma unroll
            for (int q = 0; q < 8; q++) { a[q] = As[kk][ty + 16 * q]; b[q] = Bs[kk][tx + 16 * q]; }
#pragma unroll
            for (int q = 0; q < 8; q++)
#pragma unroll
                for (int r = 0; r < 8; r++) acc[q][r] += a[q] * b[r];
        }
        __syncthreads();
    }
#pragma unroll
    for (int q = 0; q < 8; q++)
#pragma unroll
        for (int r = 0; r < 8; r++) {
            int row = I0 + ty + 16 * q, col = J0 + tx + 16 * r;
            long idx = (long)row * ldc + col;
            float v = alpha * acc[q][r];
            if (accum == 1) v += Cp[idx];
            if (accum == 2) v += Dp[idx];
            Cp[idx] = v;
            if (mir) Cp[(long)col * ldc + row] = v;
        }
}

// split fp32 G -> bf16 hi + bf16 lo planes
__global__ __launch_bounds__(256) void k_gsplit(const float* __restrict__ G,
                                                ushort_t* __restrict__ hi,
                                                ushort_t* __restrict__ lo) {
    long idx = ((long)blockIdx.x * 256 + threadIdx.x) * 4;
    float4 g = *(const float4*)(G + idx);
    v4us h, l;
    float gv[4] = {g.x, g.y, g.z, g.w};
#pragma unroll
    for (int e = 0; e < 4; e++) {
        unsigned int u = __float_as_uint(gv[e]);
        unsigned short hb = (unsigned short)(u >> 16);
        float hf = __uint_as_float((unsigned int)hb << 16);
        float r = gv[e] - hf;
        unsigned short lb = (unsigned short)(__float_as_uint(r) >> 16);
        h[e] = hb;
        l[e] = lb;
    }
    *(v4us*)(hi + idx) = h;
    *(v4us*)(lo + idx) = l;
}

// fused final kernel (MFMA): per (pair, 64-col b-tile):
// build K tile bf16 in LDS (transposed), Y = (Ghi+Glo) @ K via mfma 32x32x16,
// q[b] = diag(K^T Y), mu[b] = K^T c (fp32 during build), var = sf2 - q
#define KTP 280  // padded row length (bf16 elems) of KbT; 560B = 16B-aligned
__global__ __launch_bounds__(256) void k_kb3(const float* __restrict__ ZS, const float* __restrict__ ZN,
                                             const float* __restrict__ XS, const float* __restrict__ XN,
                                             const float* __restrict__ SF2,
                                             const ushort_t* __restrict__ Ghi,
                                             const ushort_t* __restrict__ Glo,
                                             const float* __restrict__ CV, float* __restrict__ out) {
    int bt = blockIdx.x;    // 16 tiles of 64 b-cols
    int pair = blockIdx.y;  // 128
    int h = pair >> 5;
    int t = threadIdx.x;
    int w = t >> 6;         // wave id 0..3
    int lane = t & 63;
    int l31 = lane & 31, lhalf = lane >> 5;

    __shared__ __align__(16) ushort_t KbT[64][KTP];  // [b][j] bf16
    __shared__ float qpart[4][64];
    __shared__ float mup[4][64];

    float sf2 = SF2[h];

    // ---- build phase: thread (w, b=t&63) computes K(z_j, x_b) for j in [w*64, w*64+64)
    {
        int b = t & 63;
        long bg = (long)h * B_ + bt * 64 + b;
        const float4* xrow = (const float4*)(XS + bg * 16);
        float4 x0 = xrow[0], x1 = xrow[1], x2 = xrow[2], x3 = xrow[3];
        float xn = XN[bg];
        float mupart = 0.f;
        const float* cvp = CV + pair * 256;
        const float* znp = ZN + pair * 256;
#pragma unroll 2
        for (int j8 = 0; j8 < 8; j8++) {
            v8us kb8;
#pragma unroll
            for (int e = 0; e < 8; e++) {
                int j = w * 64 + j8 * 8 + e;
                const float4* zrow = (const float4*)(ZS + ((long)pair * 256 + j) * 16);
                float4 z0 = zrow[0], z1 = zrow[1], z2 = zrow[2], z3 = zrow[3];
                float dot = z0.x * x0.x + z0.y * x0.y + z0.z * x0.z + z0.w * x0.w +
                            z1.x * x1.x + z1.y * x1.y + z1.z * x1.z + z1.w * x1.w +
                            z2.x * x2.x + z2.y * x2.y + z2.z * x2.z + z2.w * x2.w +
                            z3.x * x3.x + z3.y * x3.y + z3.z * x3.z + z3.w * x3.w;
                float d2 = fmaxf(znp[j] + xn - 2.f * dot, 0.f);
                float kv = sf2 * __expf(-0.5f * d2);
                mupart += cvp[j] * kv;
                unsigned int u = __float_as_uint(kv);
                u += 0x7fffu + ((u >> 16) & 1u);  // RNE to bf16
                kb8[e] = (unsigned short)(u >> 16);
            }
            *(v8us*)&KbT[b][w * 64 + j8 * 8] = kb8;
        }
        mup[w][b] = mupart;
    }
    __syncthreads();

    // ---- MFMA phase: Y[i=256][b=64]; wave w owns i in [w*64, w*64+64)
    v16f acc[2][2];
#pragma unroll
    for (int mt = 0; mt < 2; mt++)
#pragma unroll
        for (int nt = 0; nt < 2; nt++)
#pragma unroll
            for (int r = 0; r < 16; r++) acc[mt][nt][r] = 0.f;

    const ushort_t* GhiP = Ghi + (long)pair * 65536;
    const ushort_t* GloP = Glo + (long)pair * 65536;
    for (int k0 = 0; k0 < 256; k0 += 16) {
        v8bf bfr[2];
#pragma unroll
        for (int nt = 0; nt < 2; nt++)
            bfr[nt] = *(const v8bf*)&KbT[nt * 32 + l31][k0 + lhalf * 8];
#pragma unroll
        for (int mt = 0; mt < 2; mt++) {
            int i = w * 64 + mt * 32 + l31;
            v8bf ah = *(const v8bf*)(GhiP + (long)i * 256 + k0 + lhalf * 8);
            v8bf al = *(const v8bf*)(GloP + (long)i * 256 + k0 + lhalf * 8);
#pragma unroll
            for (int nt = 0; nt < 2; nt++) {
                acc[mt][nt] = __builtin_amdgcn_mfma_f32_32x32x16_bf16(ah, bfr[nt], acc[mt][nt], 0, 0, 0);
                acc[mt][nt] = __builtin_amdgcn_mfma_f32_32x32x16_bf16(al, bfr[nt], acc[mt][nt], 0, 0, 0);
            }
        }
    }

    // ---- reduction: q_b += K_ib * Y_ib over this wave's i-range
    float qp[2] = {0.f, 0.f};
#pragma unroll
    for (int mt = 0; mt < 2; mt++) {
#pragma unroll
        for (int nt = 0; nt < 2; nt++) {
            int b = nt * 32 + l31;
#pragma unroll
            for (int g = 0; g < 4; g++) {
                int ibase = w * 64 + mt * 32 + 8 * g + 4 * lhalf;
                v4us k4 = *(const v4us*)&KbT[b][ibase];
#pragma unroll
                for (int e = 0; e < 4; e++) {
                    float kv = __uint_as_float((unsigned int)k4[e] << 16);
                    qp[nt] += kv * acc[mt][nt][4 * g + e];
                }
            }
        }
    }
#pragma unroll
    for (int nt = 0; nt < 2; nt++) {
        qp[nt] += __shfl_down(qp[nt], 32, 64);
        if (lhalf == 0) qpart[w][nt * 32 + l31] = qp[nt];
    }
    __syncthreads();

    if (t < 64) {
        float mu = mup[0][t] + mup[1][t] + mup[2][t] + mup[3][t];
        float q = qpart[0][t] + qpart[1][t] + qpart[2][t] + qpart[3][t];
        long ob = (long)pair * 1024 + bt * 64 + t;
        out[ob] = mu;
        out[(long)H_ * O_ * B_ + ob] = sf2 - q;
    }
}

// ---------------------------------------------------------------------------
extern "C" void kernel_launch(void* const* d_in, const int* in_sizes, int n_in,
                              void* d_out, int out_size, void* d_ws, size_t ws_size,
                              hipStream_t stream) {
    const float* x = (const float*)d_in[0];
    const float* z = (const float*)d_in[1];
    const float* u_mean = (const float*)d_in[2];
    const float* u_tril_vec = (const float*)d_in[3];
    const float* m_old = (const float*)d_in[4];
    const float* L_old = (const float*)d_in[5];
    const float* z_old = (const float*)d_in[6];
    const float* theta = (const float*)d_in[7];

    const long BIGSZ = (long)HO * M2 * M2;  // 8388608
    const long MSZ = (long)HO * M_ * M_;    // 2097152
    const long OSZ = (long)O_ * M_ * M_;    // 524288
    const long SH2 = (long)O_ * M2 * M2;    // per-h stride of big arrays
    const long SO2 = (long)M2 * M2;
    const long SH1 = (long)O_ * M_ * M_;
    const long SO1 = (long)M_ * M_;

    float* ws = (float*)d_ws;
    long off = 0;
    float* BIG0 = ws + off; off += BIGSZ;  // KUU2 -> AINV
    float* BIG1 = ws + off; off += BIGSZ;  // UT -> COVj -> G
    float* BIG2 = ws + off; off += BIGSZ;  // Linv128|A1|A3|ATX (then TRb,BRb) -> LINV
    float* BIG3 = ws + off; off += BIGSZ;  // L256 -> P -> Ghi/Glo(bf16)
    float* SOLD = ws + off; off += OSZ;
    float* SCUR = ws + off; off += OSZ;
    float* ZS = ws + off; off += (long)HO * M2 * D_;
    float* XS = ws + off; off += (long)H_ * B_ * D_;
    float* ZN = ws + off; off += (long)HO * M2;
    float* XN = ws + off; off += (long)H_ * B_;
    float* MJ = ws + off; off += (long)HO * M2;
    float* CV = ws + off; off += (long)HO * M2;
    float* LSI = ws + off; off += H_ * D_;
    float* SF2v = ws + off; off += H_;

    float* UT = BIG1;
    float* KUU2 = BIG0;
    float* COV = BIG1;
    float* Linv128 = BIG2;            // slot 0
    float* A1 = BIG2 + MSZ;           // slot 1
    float* A3 = BIG2 + 2 * MSZ;       // slot 2
    float* ATX = BIG2 + 3 * MSZ;      // slot 3
    float* TRb = BIG2 + 2 * MSZ;      // reuse slot 2 (A3 dead)
    float* BRb = BIG2;                // reuse slot 0 (Linv128 dead)
    float* L256 = BIG3;
    float* LINV = BIG2;
    float* AINV = BIG0;
    float* Pb = BIG3;
    float* Gb = BIG1;
    ushort_t* Ghi = (ushort_t*)BIG3;  // P dead after G computed
    ushort_t* Glo = Ghi + BIGSZ;
    const long BRoff = 128L * M2 + 128;  // BR quadrant offset in a 256x256

    k_prep<<<1, 64, 0, stream>>>(theta, LSI, SF2v);
    k_scale_x<<<(H_ * B_ + 255) / 256, 256, 0, stream>>>(x, LSI, XS, XN);
    k_scale_z<<<HO * M2 / 256, 256, 0, stream>>>(z, z_old, LSI, ZS, ZN);
    k_unpack<<<(int)(OSZ / 256), 256, 0, stream>>>(u_tril_vec, UT);

    // S_old = L_old L_old^T ; S_cur = UT UT^T   (batched over o)
    k_bmm<0, 1><<<dim3(O_, 1, 1), 256, 0, stream>>>(L_old, 0, SO1, M_, L_old, 0, SO1, M_,
                                                    SOLD, 0, SO1, M_, nullptr, M_, 0, 0, 1.f, 0, 0);
    k_bmm<0, 1><<<dim3(O_, 1, 1), 256, 0, stream>>>(UT, 0, SO1, M_, UT, 0, SO1, M_,
                                                    SCUR, 0, SO1, M_, nullptr, M_, 0, 0, 1.f, 0, 0);

    k_kuu2<<<HO, 256, 0, stream>>>(ZS, ZN, SF2v, KUU2);
    // chol of TL 128x128 -> L256 TL
    k_chol128<<<HO, 256, 0, stream>>>(KUU2, SO2, M2, L256, SO2, M2);

    hipMemsetAsync(Linv128, 0, MSZ * sizeof(float), stream);
    k_diaginv<<<dim3(HO, 2), 64, 0, stream>>>(L256, SO2, M2, Linv128, SO1, M_);
    k_linvoff<<<dim3(HO, 1), 256, 0, stream>>>(L256, SO2, M2, Linv128, SO1, M_, 1);

    // A1 = Linv128 @ kuf (kuf = KUU2 rows 0..127, cols 128..255)
    k_bmm<0, 0><<<dim3(HO, 1, 1), 256, 0, stream>>>(Linv128, SH1, SO1, M_,
                                                    KUU2 + 128, SH2, SO2, M2,
                                                    A1, SH1, SO1, M_, nullptr, M_, 0, 0, 1.f, 0, 0);
    // A3 = Linv128 @ L_old
    k_bmm<0, 0><<<dim3(HO, 1, 1), 256, 0, stream>>>(Linv128, SH1, SO1, M_, L_old, 0, SO1, M_,
                                                    A3, SH1, SO1, M_, nullptr, M_, 0, 0, 1.f, 0, 0);
    k_stage1vec<<<HO, 128, 0, stream>>>(Linv128, A1, m_old, u_mean, MJ);

    // ATX = A3^T @ A1
    k_bmm<1, 0><<<dim3(HO, 1, 1), 256, 0, stream>>>(A3, SH1, SO1, M_, A1, SH1, SO1, M_,
                                                    ATX, SH1, SO1, M_, nullptr, M_, 0, 0, 1.f, 0, 0);
    // TRb = L_old @ ATX   (overwrites A3 slot — A3 dead)
    k_bmm<0, 0><<<dim3(HO, 1, 1), 256, 0, stream>>>(L_old, 0, SO1, M_, ATX, SH1, SO1, M_,
                                                    TRb, SH1, SO1, M_, nullptr, M_, 0, 0, 1.f, 0, 0);
    // BRb = ATX^T @ ATX   (overwrites Linv128 slot — dead after stage1vec/A1/A3)
    k_bmm<1, 0><<<dim3(HO, 1, 1), 256, 0, stream>>>(ATX, SH1, SO1, M_, ATX, SH1, SO1, M_,
                                                    BRb, SH1, SO1, M_, nullptr, M_, 0, 0, 1.f, 0, 0);

    k_assemble<<<dim3(HO, 4), 256, 0, stream>>>(SOLD, SCUR, TRb, BRb, COV);

    // L256 BL = A1^T
    k_copyT<<<HO, 256, 0, stream>>>(A1, L256);
    // Schur: KUU2_BR -= A1^T A1
    k_bmm<1, 0><<<dim3(HO, 1, 1), 256, 0, stream>>>(A1, SH1, SO1, M_, A1, SH1, SO1, M_,
                                                    KUU2 + BRoff, SH2, SO2, M2, nullptr,
                                                    M_, 0, 0, -1.f, 1, 0);
    // L22 = chol(S22) -> L256 BR
    k_chol128<<<HO, 256, 0, stream>>>(KUU2 + BRoff, SO2, M2, L256 + BRoff, SO2, M2);

    // LINV = L256^{-1}  (overwrites all of BIG2; A1/TRb/BRb consumed above)
    hipMemsetAsync(LINV, 0, BIGSZ * sizeof(float), stream);
    k_diaginv<<<dim3(HO, 4), 64, 0, stream>>>(L256, SO2, M2, LINV, SO2, M2);
    k_linvoff<<<dim3(HO, 3), 256, 0, stream>>>(L256, SO2, M2, LINV, SO2, M2, 1);
    k_linvoff<<<dim3(HO, 2), 256, 0, stream>>>(L256, SO2, M2, LINV, SO2, M2, 2);
    k_linvoff<<<dim3(HO, 1), 256, 0, stream>>>(L256, SO2, M2, LINV, SO2, M2, 3);

    k_cvec<<<HO, 256, 0, stream>>>(LINV, MJ, CV);

    // AINV = LINV^T @ LINV  (symmetric: 3 tiles + mirror; k >= max(I0,J0))
    k_bmm<1, 0><<<dim3(HO, 3, 1), 256, 0, stream>>>(LINV, SH2, SO2, M2, LINV, SH2, SO2, M2,
                                                    AINV, SH2, SO2, M2, nullptr,
                                                    M2, 3, 0, 1.f, 0, 1);
    // P = COVj @ AINV  (L256 dead -> BIG3)
    k_bmm<0, 0><<<dim3(HO, 2, 2), 256, 0, stream>>>(COV, SH2, SO2, M2, AINV, SH2, SO2, M2,
                                                    Pb, SH2, SO2, M2, nullptr,
                                                    M2, 0, 0, 1.f, 0, 0);
    // G = AINV - P^T @ AINV  (symmetric: 3 tiles + mirror; COVj dead -> BIG1)
    k_bmm<1, 0><<<dim3(HO, 3, 1), 256, 0, stream>>>(Pb, SH2, SO2, M2, AINV, SH2, SO2, M2,
                                                    Gb, SH2, SO2, M2, AINV,
                                                    M2, 0, 0, -1.f, 2, 1);

    // split G into bf16 hi/lo planes (P dead -> BIG3)
    k_gsplit<<<(int)(BIGSZ / 1024), 256, 0, stream>>>(Gb, Ghi, Glo);

    k_kb3<<<dim3(16, HO), 256, 0, stream>>>(ZS, ZN, XS, XN, SF2v, Ghi, Glo, CV, (float*)d_out);
}